// Round 3
// baseline (3797.003 us; speedup 1.0000x reference)
//
#include <hip/hip_runtime.h>
#include <cfloat>

#define HD 64
#define N_NETN 100000
#define N_PIN  400000
#define N_PON  200000
#define N_CELLN 200000
#define E1 400000
#define E2 400000
#define E3 200000
#define E4 200000
#define E_TOT (E1+E2+E3+E4)

// dst-segment node bases (concatenated dst node spaces: pi, cell, po, net)
#define PB_PI 0
#define PB_CELL (N_PIN)
#define PB_PO (N_PIN + N_CELLN)
#define PB_NET (N_PIN + N_CELLN + N_PON)
#define NT_DST (N_PIN + N_CELLN + N_PON + N_NETN)   // 900000

// src-degree segment bases (concatenated src node spaces per edge set)
#define SB1 0
#define SB2 (N_NETN)
#define SB3 (N_NETN + N_PIN)
#define SB4 (N_NETN + N_PIN + N_CELLN)
#define SRC_TOT (N_NETN + N_PIN + N_CELLN + N_PON)  // 900000

#define SCAN_CHUNK 4096
#define NB_CHUNKS ((NT_DST + SCAN_CHUNK - 1) / SCAN_CHUNK)  // 220 (<=256)

typedef unsigned short bfr;  // raw bf16 storage

__device__ __forceinline__ float b2f(bfr u) {
    return __uint_as_float(((unsigned)u) << 16);
}
__device__ __forceinline__ bfr f2b(float f) {
    unsigned u = __float_as_uint(f);
    unsigned r = (u + 0x7FFFu + ((u >> 16) & 1u)) >> 16;   // RNE
    return (bfr)r;
}

// ---------------------------------------------------------------- histograms
__global__ void k_hist(const int* __restrict__ idx, int n, int* __restrict__ cnt) {
    int i = blockIdx.x * blockDim.x + threadIdx.x;
    if (i < n) atomicAdd(&cnt[idx[i]], 1);
}

// in-place int count -> float reciprocal (inv aliases cnt; each thread touches only slot i)
__global__ void k_invdeg(const int* cnt, float* inv, int n) {
    int i = blockIdx.x * blockDim.x + threadIdx.x;
    if (i < n) {
        int c = cnt[i];
        inv[i] = 1.0f / (float)max(c, 1);
    }
}

// ---------------------------------------------------------------- scan (exclusive over NT_DST counts)
__global__ void k_scanA(const int* __restrict__ in, int n, int* __restrict__ bsum) {
    __shared__ int sh[256];
    int t = threadIdx.x, b = blockIdx.x;
    int base = b * SCAN_CHUNK + t * 16;
    int s = 0;
#pragma unroll
    for (int u = 0; u < 16; ++u) { int i = base + u; s += (i < n) ? in[i] : 0; }
    sh[t] = s; __syncthreads();
    for (int off = 128; off > 0; off >>= 1) { if (t < off) sh[t] += sh[t + off]; __syncthreads(); }
    if (t == 0) bsum[b] = sh[0];
}

__global__ void k_scanB(int* __restrict__ bsum, int nb) {
    __shared__ int sh[256];
    int t = threadIdx.x;
    int v = (t < nb) ? bsum[t] : 0;
    sh[t] = v; __syncthreads();
    for (int off = 1; off < 256; off <<= 1) {
        int add = (t >= off) ? sh[t - off] : 0;
        __syncthreads();
        sh[t] += add;
        __syncthreads();
    }
    if (t < nb) bsum[t] = sh[t] - v;  // exclusive
}

__global__ void k_scanC(const int* __restrict__ in, int n, const int* __restrict__ bsum,
                        int* __restrict__ rp) {
    __shared__ int sh[256];
    int t = threadIdx.x, b = blockIdx.x;
    int base = b * SCAN_CHUNK + t * 16;
    int x[16]; int s = 0;
#pragma unroll
    for (int u = 0; u < 16; ++u) { int i = base + u; x[u] = (i < n) ? in[i] : 0; s += x[u]; }
    sh[t] = s; __syncthreads();
    int mine = s;
    for (int off = 1; off < 256; off <<= 1) {
        int add = (t >= off) ? sh[t - off] : 0;
        __syncthreads();
        sh[t] += add;
        __syncthreads();
    }
    int run = bsum[b] + sh[t] - mine;   // exclusive offset for this thread's 16 elems
#pragma unroll
    for (int u = 0; u < 16; ++u) { int i = base + u; if (i < n) rp[i] = run; run += x[u]; }
    if (b == 0 && t == 0) rp[n] = E_TOT;
}

__global__ void k_fill(const int* __restrict__ src, const int* __restrict__ dst, int n,
                       int node_base, int* __restrict__ cursor, int* __restrict__ col) {
    int i = blockIdx.x * blockDim.x + threadIdx.x;
    if (i < n) {
        int p = atomicAdd(&cursor[node_base + dst[i]], 1);
        col[p] = src[i];
    }
}

// copy rp -> cursor (cursor aliases ccnt, which is dead after the scan)
__global__ void k_copy(const int* __restrict__ a, int* __restrict__ b, int n) {
    int i = blockIdx.x * blockDim.x + threadIdx.x;
    if (i < n) b[i] = a[i];
}

// ---------------------------------------------------------------- init embeddings (bf16 storage)
__global__ void k_init_net(const float* __restrict__ x, const float* __restrict__ w,
                           const float* __restrict__ b, bfr* __restrict__ out, int n) {
    int gw = (blockIdx.x * blockDim.x + threadIdx.x) >> 6;
    int lane = threadIdx.x & 63;
    if (gw >= n) return;
    float w0 = w[lane], w1 = w[64 + lane], w2 = w[128 + lane], w3 = w[192 + lane];
    float4 xv = ((const float4*)x)[gw];
    float y = b[lane];
    y = fmaf(xv.x, w0, y); y = fmaf(xv.y, w1, y); y = fmaf(xv.z, w2, y); y = fmaf(xv.w, w3, y);
    out[gw * 64 + lane] = f2b(fmaxf(y, 0.f));
}

__global__ void k_init_p3(const float* __restrict__ x, const float* __restrict__ w,
                          const float* __restrict__ b, bfr* __restrict__ out, int n) {
    int gw = (blockIdx.x * blockDim.x + threadIdx.x) >> 6;
    int lane = threadIdx.x & 63;
    if (gw >= n) return;
    float y = b[lane];
    y = fmaf(x[gw * 3 + 0], w[lane], y);
    y = fmaf(x[gw * 3 + 1], w[64 + lane], y);
    y = fmaf(x[gw * 3 + 2], w[128 + lane], y);
    out[gw * 64 + lane] = f2b(fmaxf(y, 0.f));
}

__global__ void k_init_cell(const float* __restrict__ cx, const float* __restrict__ wcs,
                            const float* __restrict__ bcs, const float* __restrict__ wct,
                            const float* __restrict__ bct, bfr* __restrict__ cell,
                            bfr* __restrict__ emb, int n) {
    int gw = (blockIdx.x * blockDim.x + threadIdx.x) >> 6;
    int lane = threadIdx.x & 63;
    if (gw >= n) return;
    const float* row = cx + (size_t)gw * 32;
    float y = bcs[lane];
#pragma unroll
    for (int k = 0; k < 6; ++k) y = fmaf(row[26 + k], wcs[k * 64 + lane], y);
    cell[gw * 64 + lane] = f2b(fmaxf(y, 0.f));
    if (lane < 8) {
        float e = bct[lane];
#pragma unroll
        for (int k = 0; k < 26; ++k) e = fmaf(row[k], wct[k * 8 + lane], e);
        emb[gw * 8 + lane] = f2b(e);
    }
}

// ---------------------------------------------------------------- fused stage: aggregate + GEMM + LN + ReLU
// block = 256 threads, 64-dst-node tile. LDS: WT 24.5KB + comb 24.5KB -> 3 blocks/CU by LDS.
__global__ __launch_bounds__(256) void k_update(
    int n_dst, bfr* __restrict__ fdst, const bfr* __restrict__ fsrc,
    const int* __restrict__ rp, const int* __restrict__ col,
    const float* __restrict__ invdeg, const float* __restrict__ W,
    const float* __restrict__ bup, const float* __restrict__ g, const float* __restrict__ be)
{
    __shared__ alignas(16) bfr WT[64][196];    // WT[f][k] = W[k*64+f], k<192
    __shared__ alignas(16) bfr comb[64][196];  // [node][ mean(64) | max(64) | min(64) ]
    int t = threadIdx.x;
    int tileBase = blockIdx.x * 64;

    for (int idx = t; idx < 192 * 64; idx += 256) {
        int k = idx >> 6, f = idx & 63;
        WT[f][k] = f2b(W[idx]);
    }

    int wave = t >> 6, lane = t & 63;
    for (int jj = 0; jj < 16; ++jj) {
        int nl = wave * 16 + jj;
        int v = tileBase + nl;
        float acc = 0.f, mx = -FLT_MAX, mn = FLT_MAX;
        int cnt = 0;
        if (v < n_dst) {
            int e0 = rp[v], e1 = rp[v + 1];
            cnt = e1 - e0;
            for (int e = e0; e < e1; ++e) {
                int s = col[e];
                float wg = invdeg[s];
                float xv = b2f(fsrc[s * 64 + lane]);
                acc = fmaf(wg, xv, acc);
                mx = fmaxf(mx, xv);
                mn = fminf(mn, xv);
            }
        }
        if (cnt == 0) { mx = 0.f; mn = 0.f; }
        comb[nl][lane] = f2b(acc);
        comb[nl][64 + lane] = f2b(mx);
        comb[nl][128 + lane] = f2b(mn);
    }
    __syncthreads();

    int tr = t >> 4, tc = t & 15;
    float y[4][4] = {};
    for (int k0 = 0; k0 < 192; k0 += 4) {
        float a[4][4], bb[4][4];
#pragma unroll
        for (int i = 0; i < 4; ++i) {
            ushort4 av = *(const ushort4*)&comb[tr + 16 * i][k0];
            a[i][0] = b2f(av.x); a[i][1] = b2f(av.y); a[i][2] = b2f(av.z); a[i][3] = b2f(av.w);
        }
#pragma unroll
        for (int j = 0; j < 4; ++j) {
            ushort4 bv = *(const ushort4*)&WT[tc + 16 * j][k0];
            bb[j][0] = b2f(bv.x); bb[j][1] = b2f(bv.y); bb[j][2] = b2f(bv.z); bb[j][3] = b2f(bv.w);
        }
#pragma unroll
        for (int i = 0; i < 4; ++i)
#pragma unroll
            for (int j = 0; j < 4; ++j) {
                y[i][j] = fmaf(a[i][0], bb[j][0], y[i][j]);
                y[i][j] = fmaf(a[i][1], bb[j][1], y[i][j]);
                y[i][j] = fmaf(a[i][2], bb[j][2], y[i][j]);
                y[i][j] = fmaf(a[i][3], bb[j][3], y[i][j]);
            }
    }

#pragma unroll
    for (int i = 0; i < 4; ++i) {
        int v = tileBase + tr + 16 * i;
        if (v >= n_dst) continue;        // uniform across the 16-lane shuffle group
        float z[4], s1 = 0.f, s2 = 0.f;
#pragma unroll
        for (int j = 0; j < 4; ++j) {
            int f = tc + 16 * j;
            z[j] = b2f(fdst[v * 64 + f]) + y[i][j] + bup[f];
            s1 += z[j];
            s2 += z[j] * z[j];
        }
        for (int m = 1; m < 16; m <<= 1) {
            s1 += __shfl_xor(s1, m);
            s2 += __shfl_xor(s2, m);
        }
        float mean = s1 * (1.f / 64.f);
        float var = s2 * (1.f / 64.f) - mean * mean;
        float rs = rsqrtf(var + 1e-5f);
#pragma unroll
        for (int j = 0; j < 4; ++j) {
            int f = tc + 16 * j;
            float o = (z[j] - mean) * rs * g[f] + be[f];
            fdst[v * 64 + f] = f2b(fmaxf(o, 0.f));
        }
    }
}

// ---------------------------------------------------------------- cell_out MLP (two chained GEMMs)
__global__ __launch_bounds__(256) void k_mlp(
    const bfr* __restrict__ cell, const bfr* __restrict__ emb,
    const float* __restrict__ W1, const float* __restrict__ b1,
    const float* __restrict__ W2, const float* __restrict__ b2,
    bfr* __restrict__ cout)
{
    __shared__ alignas(16) bfr A[64][76];     // [node][cell(64)|emb(8)]
    __shared__ alignas(16) bfr W1T[64][76];   // W1T[f][k], k<72
    __shared__ alignas(16) bfr W2T[64][68];   // W2T[f][k], k<64
    __shared__ alignas(16) bfr Hb[64][68];    // hidden
    int t = threadIdx.x;
    int base = blockIdx.x * 64;

    for (int idx = t; idx < 72 * 64; idx += 256) { int k = idx >> 6, f = idx & 63; W1T[f][k] = f2b(W1[idx]); }
    for (int idx = t; idx < 64 * 64; idx += 256) { int k = idx >> 6, f = idx & 63; W2T[f][k] = f2b(W2[idx]); }
    for (int idx = t; idx < 64 * 64; idx += 256) { A[idx >> 6][idx & 63] = cell[(size_t)base * 64 + idx]; }
    for (int idx = t; idx < 64 * 8;  idx += 256) { A[idx >> 3][64 + (idx & 7)] = emb[(size_t)base * 8 + idx]; }
    __syncthreads();

    int tr = t >> 4, tc = t & 15;
    float y[4][4] = {};
    for (int k0 = 0; k0 < 72; k0 += 4) {
        float a[4][4], bb[4][4];
#pragma unroll
        for (int i = 0; i < 4; ++i) {
            ushort4 av = *(const ushort4*)&A[tr + 16 * i][k0];
            a[i][0] = b2f(av.x); a[i][1] = b2f(av.y); a[i][2] = b2f(av.z); a[i][3] = b2f(av.w);
        }
#pragma unroll
        for (int j = 0; j < 4; ++j) {
            ushort4 bv = *(const ushort4*)&W1T[tc + 16 * j][k0];
            bb[j][0] = b2f(bv.x); bb[j][1] = b2f(bv.y); bb[j][2] = b2f(bv.z); bb[j][3] = b2f(bv.w);
        }
#pragma unroll
        for (int i = 0; i < 4; ++i)
#pragma unroll
            for (int j = 0; j < 4; ++j) {
                y[i][j] = fmaf(a[i][0], bb[j][0], y[i][j]);
                y[i][j] = fmaf(a[i][1], bb[j][1], y[i][j]);
                y[i][j] = fmaf(a[i][2], bb[j][2], y[i][j]);
                y[i][j] = fmaf(a[i][3], bb[j][3], y[i][j]);
            }
    }
#pragma unroll
    for (int i = 0; i < 4; ++i)
#pragma unroll
        for (int j = 0; j < 4; ++j) {
            int f = tc + 16 * j;
            Hb[tr + 16 * i][f] = f2b(fmaxf(y[i][j] + b1[f], 0.f));
        }
    __syncthreads();

    float y2[4][4] = {};
    for (int k0 = 0; k0 < 64; k0 += 4) {
        float a[4][4], bb[4][4];
#pragma unroll
        for (int i = 0; i < 4; ++i) {
            ushort4 av = *(const ushort4*)&Hb[tr + 16 * i][k0];
            a[i][0] = b2f(av.x); a[i][1] = b2f(av.y); a[i][2] = b2f(av.z); a[i][3] = b2f(av.w);
        }
#pragma unroll
        for (int j = 0; j < 4; ++j) {
            ushort4 bv = *(const ushort4*)&W2T[tc + 16 * j][k0];
            bb[j][0] = b2f(bv.x); bb[j][1] = b2f(bv.y); bb[j][2] = b2f(bv.z); bb[j][3] = b2f(bv.w);
        }
#pragma unroll
        for (int i = 0; i < 4; ++i)
#pragma unroll
            for (int j = 0; j < 4; ++j) {
                y2[i][j] = fmaf(a[i][0], bb[j][0], y2[i][j]);
                y2[i][j] = fmaf(a[i][1], bb[j][1], y2[i][j]);
                y2[i][j] = fmaf(a[i][2], bb[j][2], y2[i][j]);
                y2[i][j] = fmaf(a[i][3], bb[j][3], y2[i][j]);
            }
    }
#pragma unroll
    for (int i = 0; i < 4; ++i)
#pragma unroll
        for (int j = 0; j < 4; ++j) {
            int f = tc + 16 * j;
            cout[(size_t)(base + tr + 16 * i) * 64 + f] = f2b(y2[i][j] + b2[f]);
        }
}

// ---------------------------------------------------------------- final projection (fp32 output)
__global__ void k_final(const bfr* __restrict__ net, const float* __restrict__ w,
                        const float* __restrict__ b, float* __restrict__ out, int n) {
    int gw = (blockIdx.x * blockDim.x + threadIdx.x) >> 6;
    int lane = threadIdx.x & 63;
    if (gw >= n) return;
    float p = b2f(net[gw * 64 + lane]) * w[lane];
    for (int m = 1; m < 64; m <<= 1) p += __shfl_xor(p, m);
    if (lane == 0) out[gw] = p + b[0];
}

// ---------------------------------------------------------------- launcher
extern "C" void kernel_launch(void* const* d_in, const int* in_sizes, int n_in,
                              void* d_out, int out_size, void* d_ws, size_t ws_size,
                              hipStream_t stream) {
    const float* net_x    = (const float*)d_in[0];
    const float* pin_in_x = (const float*)d_in[1];
    const float* pin_out_x= (const float*)d_in[2];
    const float* cell_x   = (const float*)d_in[3];
    const int* src1 = (const int*)d_in[4];
    const int* dst1 = (const int*)d_in[5];
    const int* src2 = (const int*)d_in[6];
    const int* dst2 = (const int*)d_in[7];
    const int* src3 = (const int*)d_in[8];
    const int* dst3 = (const int*)d_in[9];
    const int* src4 = (const int*)d_in[10];
    const int* dst4 = (const int*)d_in[11];
    const float* w_ct = (const float*)d_in[12];
    const float* b_ct = (const float*)d_in[13];
    const float* w_net = (const float*)d_in[14];
    const float* b_net = (const float*)d_in[15];
    const float* w_pi = (const float*)d_in[16];
    const float* b_pi = (const float*)d_in[17];
    const float* w_po = (const float*)d_in[18];
    const float* b_po = (const float*)d_in[19];
    const float* w_cs = (const float*)d_in[20];
    const float* b_cs = (const float*)d_in[21];
    const float* g_net = (const float*)d_in[22];
    const float* be_net = (const float*)d_in[23];
    const float* g_pi = (const float*)d_in[24];
    const float* be_pi = (const float*)d_in[25];
    const float* g_po = (const float*)d_in[26];
    const float* be_po = (const float*)d_in[27];
    const float* g_cell = (const float*)d_in[28];
    const float* be_cell = (const float*)d_in[29];
    const float* w_net_up = (const float*)d_in[30];
    const float* b_net_up = (const float*)d_in[31];
    const float* w_pi_up = (const float*)d_in[32];
    const float* b_pi_up = (const float*)d_in[33];
    const float* w_po_up = (const float*)d_in[34];
    const float* b_po_up = (const float*)d_in[35];
    const float* w_cell_up = (const float*)d_in[36];
    const float* b_cell_up = (const float*)d_in[37];
    const float* w_mlp1 = (const float*)d_in[38];
    const float* b_mlp1 = (const float*)d_in[39];
    const float* w_mlp2 = (const float*)d_in[40];
    const float* b_mlp2 = (const float*)d_in[41];
    const float* w_out = (const float*)d_in[42];
    const float* b_out = (const float*)d_in[43];

    // workspace carve-up (256B aligned)
    size_t off = 0;
    auto take = [&](size_t bytes) {
        size_t c = off;
        off += (bytes + 255) & ~(size_t)255;
        return c;
    };
    char* ws = (char*)d_ws;
    bfr* f_net  = (bfr*)(ws + take((size_t)N_NETN * 64 * 2));
    bfr* f_pi   = (bfr*)(ws + take((size_t)N_PIN * 64 * 2));
    bfr* f_po   = (bfr*)(ws + take((size_t)N_PON * 64 * 2));
    bfr* f_cell = (bfr*)(ws + take((size_t)N_CELLN * 64 * 2));
    bfr* f_cout = (bfr*)(ws + take((size_t)N_CELLN * 64 * 2));
    bfr* f_emb  = (bfr*)(ws + take((size_t)N_CELLN * 8 * 2));
    int*   dcnt   = (int*)(ws + take((size_t)SRC_TOT * 4));
    float* invd   = (float*)dcnt;                 // aliased: in-place int->float
    int*   ccnt   = (int*)(ws + take((size_t)NT_DST * 4));
    int*   cursor = ccnt;                         // aliased: ccnt dead after scan
    int*   rp     = (int*)(ws + take((size_t)(NT_DST + 1) * 4));
    int*   col    = (int*)(ws + take((size_t)E_TOT * 4));
    int*   bsum   = (int*)(ws + take((size_t)NB_CHUNKS * 4));
    (void)in_sizes; (void)n_in; (void)out_size;

    // If the workspace is too small, bail out cleanly (output stays 0 ->
    // clean absmax failure instead of a GPU memory fault).
    if (ws_size < off) return;

    dim3 B(256);
    auto cdiv = [](int a, int b) { return (a + b - 1) / b; };

    hipMemsetAsync(dcnt, 0, (size_t)SRC_TOT * 4, stream);
    hipMemsetAsync(ccnt, 0, (size_t)NT_DST * 4, stream);

    // source-degree histograms + reciprocals (in place)
    k_hist<<<cdiv(E1, 256), B, 0, stream>>>(src1, E1, dcnt + SB1);
    k_hist<<<cdiv(E2, 256), B, 0, stream>>>(src2, E2, dcnt + SB2);
    k_hist<<<cdiv(E3, 256), B, 0, stream>>>(src3, E3, dcnt + SB3);
    k_hist<<<cdiv(E4, 256), B, 0, stream>>>(src4, E4, dcnt + SB4);
    k_invdeg<<<cdiv(SRC_TOT, 256), B, 0, stream>>>(dcnt, invd, SRC_TOT);

    // dst histograms -> CSR row_ptr (global exclusive scan over concatenated counts)
    k_hist<<<cdiv(E1, 256), B, 0, stream>>>(dst1, E1, ccnt + PB_PI);
    k_hist<<<cdiv(E2, 256), B, 0, stream>>>(dst2, E2, ccnt + PB_CELL);
    k_hist<<<cdiv(E3, 256), B, 0, stream>>>(dst3, E3, ccnt + PB_PO);
    k_hist<<<cdiv(E4, 256), B, 0, stream>>>(dst4, E4, ccnt + PB_NET);
    k_scanA<<<NB_CHUNKS, B, 0, stream>>>(ccnt, NT_DST, bsum);
    k_scanB<<<1, B, 0, stream>>>(bsum, NB_CHUNKS);
    k_scanC<<<NB_CHUNKS, B, 0, stream>>>(ccnt, NT_DST, bsum, rp);
    k_copy<<<cdiv(NT_DST, 256), B, 0, stream>>>(rp, cursor, NT_DST);
    k_fill<<<cdiv(E1, 256), B, 0, stream>>>(src1, dst1, E1, PB_PI, cursor, col);
    k_fill<<<cdiv(E2, 256), B, 0, stream>>>(src2, dst2, E2, PB_CELL, cursor, col);
    k_fill<<<cdiv(E3, 256), B, 0, stream>>>(src3, dst3, E3, PB_PO, cursor, col);
    k_fill<<<cdiv(E4, 256), B, 0, stream>>>(src4, dst4, E4, PB_NET, cursor, col);

    // initial embeddings
    k_init_net<<<cdiv(N_NETN * 64, 256), B, 0, stream>>>(net_x, w_net, b_net, f_net, N_NETN);
    k_init_p3<<<cdiv(N_PIN * 64, 256), B, 0, stream>>>(pin_in_x, w_pi, b_pi, f_pi, N_PIN);
    k_init_p3<<<cdiv(N_PON * 64, 256), B, 0, stream>>>(pin_out_x, w_po, b_po, f_po, N_PON);
    k_init_cell<<<cdiv(N_CELLN * 64, 256), B, 0, stream>>>(cell_x, w_cs, b_cs, w_ct, b_ct,
                                                           f_cell, f_emb, N_CELLN);

    for (int l = 0; l < 4; ++l) {
        k_update<<<cdiv(N_PIN, 64), B, 0, stream>>>(
            N_PIN, f_pi, f_net, rp + PB_PI, col, invd + SB1, w_pi_up, b_pi_up, g_pi, be_pi);
        k_update<<<cdiv(N_CELLN, 64), B, 0, stream>>>(
            N_CELLN, f_cell, f_pi, rp + PB_CELL, col, invd + SB2, w_cell_up, b_cell_up, g_cell, be_cell);
        k_mlp<<<N_CELLN / 64, B, 0, stream>>>(f_cell, f_emb, w_mlp1, b_mlp1, w_mlp2, b_mlp2, f_cout);
        k_update<<<cdiv(N_PON, 64), B, 0, stream>>>(
            N_PON, f_po, f_cout, rp + PB_PO, col, invd + SB3, w_po_up, b_po_up, g_po, be_po);
        k_update<<<cdiv(N_NETN, 64), B, 0, stream>>>(
            N_NETN, f_net, f_po, rp + PB_NET, col, invd + SB4, w_net_up, b_net_up, g_net, be_net);
    }

    k_final<<<cdiv(N_NETN * 64, 256), B, 0, stream>>>(f_net, w_out, b_out, (float*)d_out, N_NETN);
}

// Round 7
// 3633.522 us; speedup vs baseline: 1.0450x; 1.0450x over previous
//
#include <hip/hip_runtime.h>
#include <cfloat>

#define HD 64
#define N_NETN 100000
#define N_PIN  400000
#define N_PON  200000
#define N_CELLN 200000
#define E1 400000
#define E2 400000
#define E3 200000
#define E4 200000
#define E_TOT (E1+E2+E3+E4)

#define PB_PI 0
#define PB_CELL (N_PIN)
#define PB_PO (N_PIN + N_CELLN)
#define PB_NET (N_PIN + N_CELLN + N_PON)
#define NT_DST (N_PIN + N_CELLN + N_PON + N_NETN)   // 900000

#define SB1 0
#define SB2 (N_NETN)
#define SB3 (N_NETN + N_PIN)
#define SB4 (N_NETN + N_PIN + N_CELLN)
#define SRC_TOT (N_NETN + N_PIN + N_CELLN + N_PON)  // 900000

#define SCAN_CHUNK 4096
#define NB_CHUNKS ((NT_DST + SCAN_CHUNK - 1) / SCAN_CHUNK)  // 220 (<=256)

typedef unsigned short bfr;  // raw bf16 storage
typedef __attribute__((ext_vector_type(8))) short sh8;    // 8 bf16 (used for LDS staging copies)
typedef __attribute__((ext_vector_type(4))) float f32x4;

__device__ __forceinline__ float b2f(bfr u) {
    return __uint_as_float(((unsigned)u) << 16);
}
__device__ __forceinline__ bfr f2b(float f) {
    unsigned u = __float_as_uint(f);
    unsigned r = (u + 0x7FFFu + ((u >> 16) & 1u)) >> 16;   // RNE
    return (bfr)r;
}

// ---------------------------------------------------------------- histograms
__global__ void k_hist(const int* __restrict__ idx, int n, int* __restrict__ cnt) {
    int i = blockIdx.x * blockDim.x + threadIdx.x;
    if (i < n) atomicAdd(&cnt[idx[i]], 1);
}

__global__ void k_invdeg(const int* cnt, float* inv, int n) {
    int i = blockIdx.x * blockDim.x + threadIdx.x;
    if (i < n) {
        int c = cnt[i];
        inv[i] = 1.0f / (float)max(c, 1);
    }
}

// ---------------------------------------------------------------- scan
__global__ void k_scanA(const int* __restrict__ in, int n, int* __restrict__ bsum) {
    __shared__ int sh[256];
    int t = threadIdx.x, b = blockIdx.x;
    int base = b * SCAN_CHUNK + t * 16;
    int s = 0;
#pragma unroll
    for (int u = 0; u < 16; ++u) { int i = base + u; s += (i < n) ? in[i] : 0; }
    sh[t] = s; __syncthreads();
    for (int off = 128; off > 0; off >>= 1) { if (t < off) sh[t] += sh[t + off]; __syncthreads(); }
    if (t == 0) bsum[b] = sh[0];
}

__global__ void k_scanB(int* __restrict__ bsum, int nb) {
    __shared__ int sh[256];
    int t = threadIdx.x;
    int v = (t < nb) ? bsum[t] : 0;
    sh[t] = v; __syncthreads();
    for (int off = 1; off < 256; off <<= 1) {
        int add = (t >= off) ? sh[t - off] : 0;
        __syncthreads();
        sh[t] += add;
        __syncthreads();
    }
    if (t < nb) bsum[t] = sh[t] - v;  // exclusive
}

__global__ void k_scanC(const int* __restrict__ in, int n, const int* __restrict__ bsum,
                        int* __restrict__ rp) {
    __shared__ int sh[256];
    int t = threadIdx.x, b = blockIdx.x;
    int base = b * SCAN_CHUNK + t * 16;
    int x[16]; int s = 0;
#pragma unroll
    for (int u = 0; u < 16; ++u) { int i = base + u; x[u] = (i < n) ? in[i] : 0; s += x[u]; }
    sh[t] = s; __syncthreads();
    int mine = s;
    for (int off = 1; off < 256; off <<= 1) {
        int add = (t >= off) ? sh[t - off] : 0;
        __syncthreads();
        sh[t] += add;
        __syncthreads();
    }
    int run = bsum[b] + sh[t] - mine;
#pragma unroll
    for (int u = 0; u < 16; ++u) { int i = base + u; if (i < n) rp[i] = run; run += x[u]; }
    if (b == 0 && t == 0) rp[n] = E_TOT;
}

__global__ void k_fill(const int* __restrict__ src, const int* __restrict__ dst, int n,
                       int node_base, int* __restrict__ cursor, int* __restrict__ col) {
    int i = blockIdx.x * blockDim.x + threadIdx.x;
    if (i < n) {
        int p = atomicAdd(&cursor[node_base + dst[i]], 1);
        col[p] = src[i];
    }
}

__global__ void k_copy(const int* __restrict__ a, int* __restrict__ b, int n) {
    int i = blockIdx.x * blockDim.x + threadIdx.x;
    if (i < n) b[i] = a[i];
}

// ---------------------------------------------------------------- weight prep: fp32 [K][F] -> bf16 [F][ldout] transposed, zero-padded
__global__ void k_prepw(const float* __restrict__ w, bfr* __restrict__ out, int K, int F, int ldout) {
    int i = blockIdx.x * blockDim.x + threadIdx.x;
    int f = i / ldout, k = i - f * ldout;
    if (f < F) out[i] = (k < K) ? f2b(w[k * F + f]) : (bfr)0;
}

// ---------------------------------------------------------------- init embeddings (bf16 storage)
__global__ void k_init_net(const float* __restrict__ x, const float* __restrict__ w,
                           const float* __restrict__ b, bfr* __restrict__ out, int n) {
    int gw = (blockIdx.x * blockDim.x + threadIdx.x) >> 6;
    int lane = threadIdx.x & 63;
    if (gw >= n) return;
    float w0 = w[lane], w1 = w[64 + lane], w2 = w[128 + lane], w3 = w[192 + lane];
    float4 xv = ((const float4*)x)[gw];
    float y = b[lane];
    y = fmaf(xv.x, w0, y); y = fmaf(xv.y, w1, y); y = fmaf(xv.z, w2, y); y = fmaf(xv.w, w3, y);
    out[gw * 64 + lane] = f2b(fmaxf(y, 0.f));
}

__global__ void k_init_p3(const float* __restrict__ x, const float* __restrict__ w,
                          const float* __restrict__ b, bfr* __restrict__ out, int n) {
    int gw = (blockIdx.x * blockDim.x + threadIdx.x) >> 6;
    int lane = threadIdx.x & 63;
    if (gw >= n) return;
    float y = b[lane];
    y = fmaf(x[gw * 3 + 0], w[lane], y);
    y = fmaf(x[gw * 3 + 1], w[64 + lane], y);
    y = fmaf(x[gw * 3 + 2], w[128 + lane], y);
    out[gw * 64 + lane] = f2b(fmaxf(y, 0.f));
}

__global__ void k_init_cell(const float* __restrict__ cx, const float* __restrict__ wcs,
                            const float* __restrict__ bcs, const float* __restrict__ wct,
                            const float* __restrict__ bct, bfr* __restrict__ cell,
                            bfr* __restrict__ emb, int n) {
    int gw = (blockIdx.x * blockDim.x + threadIdx.x) >> 6;
    int lane = threadIdx.x & 63;
    if (gw >= n) return;
    const float* row = cx + (size_t)gw * 32;
    float y = bcs[lane];
#pragma unroll
    for (int k = 0; k < 6; ++k) y = fmaf(row[26 + k], wcs[k * 64 + lane], y);
    cell[gw * 64 + lane] = f2b(fmaxf(y, 0.f));
    if (lane < 8) {
        float e = bct[lane];
#pragma unroll
        for (int k = 0; k < 26; ++k) e = fmaf(row[k], wct[k * 8 + lane], e);
        emb[gw * 8 + lane] = f2b(e);
    }
}

// ---------------------------------------------------------------- fused stage: aggregate + GEMM + LN + ReLU
// BISECTION ROUND (resubmitted; r6 never ran): identical to round 5 except the
// 16 MFMAs are replaced by a scalar loop computing the SAME acc[n][j]
// quantities with the SAME output mapping (row = wave*16 + kb*4 + j,
// col = n*16 + r16). Staging, aggregation, strides, epilogue untouched.
__global__ __launch_bounds__(256) void k_update(
    int n_dst, bfr* __restrict__ fdst, const bfr* __restrict__ fsrc,
    const int* __restrict__ rp, const int* __restrict__ col,
    const float* __restrict__ invdeg, const bfr* __restrict__ wtb,
    const float* __restrict__ bup, const float* __restrict__ g, const float* __restrict__ be)
{
    __shared__ alignas(16) bfr WT[64][200];    // WT[f][k] = W[k][f] bf16, k<192
    __shared__ alignas(16) bfr comb[64][200];  // [node][ mean(64) | max(64) | min(64) ]
    int t = threadIdx.x;
    int tileBase = blockIdx.x * 64;
    int wave = t >> 6, lane = t & 63;

    // stage pre-transposed bf16 weights: 64 rows x 24 chunks of 8 = 1536 chunks
#pragma unroll
    for (int it = 0; it < 6; ++it) {
        int chunk = t + it * 256;
        int f = chunk / 24, kc = (chunk - f * 24) * 8;
        *(sh8*)&WT[f][kc] = ((const sh8*)wtb)[chunk];
    }

    // aggregation: wave handles 16 nodes, lane = feature
    for (int jj = 0; jj < 16; ++jj) {
        int nl = wave * 16 + jj;
        int v = tileBase + nl;
        float acc = 0.f, mx = -FLT_MAX, mn = FLT_MAX;
        int cnt = 0;
        if (v < n_dst) {
            int e0 = rp[v], e1 = rp[v + 1];
            cnt = e1 - e0;
            for (int e = e0; e < e1; ++e) {
                int s = col[e];
                float wg = invdeg[s];
                float xv = b2f(fsrc[s * 64 + lane]);
                acc = fmaf(wg, xv, acc);
                mx = fmaxf(mx, xv);
                mn = fminf(mn, xv);
            }
        }
        if (cnt == 0) { mx = 0.f; mn = 0.f; }
        comb[nl][lane] = f2b(acc);
        comb[nl][64 + lane] = f2b(mx);
        comb[nl][128 + lane] = f2b(mn);
    }
    __syncthreads();

    // scalar GEMM emulating the MFMA output layout exactly:
    // acc[n][j] = sum_k comb[wave*16 + kb*4 + j][k] * WT[n*16 + r16][k]
    int r16 = lane & 15, kb = lane >> 4;
    float acc[4][4];
#pragma unroll
    for (int n = 0; n < 4; ++n)
#pragma unroll
        for (int j = 0; j < 4; ++j) acc[n][j] = 0.f;
    for (int k = 0; k < 192; ++k) {
        float bv[4];
#pragma unroll
        for (int n = 0; n < 4; ++n) bv[n] = b2f(WT[n * 16 + r16][k]);
#pragma unroll
        for (int j = 0; j < 4; ++j) {
            float a = b2f(comb[wave * 16 + kb * 4 + j][k]);
#pragma unroll
            for (int n = 0; n < 4; ++n) acc[n][j] = fmaf(a, bv[n], acc[n][j]);
        }
    }

    // epilogue: row = wave*16 + kb*4 + j, col = n*16 + r16 (unchanged from r5)
#pragma unroll
    for (int j = 0; j < 4; ++j) {
        int v = tileBase + wave * 16 + kb * 4 + j;   // uniform across 16-lane shuffle group
        if (v >= n_dst) continue;
        float z[4], s1 = 0.f, s2 = 0.f;
#pragma unroll
        for (int n = 0; n < 4; ++n) {
            int f = n * 16 + r16;
            z[n] = b2f(fdst[v * 64 + f]) + acc[n][j] + bup[f];
            s1 += z[n];
            s2 += z[n] * z[n];
        }
        for (int m = 1; m < 16; m <<= 1) {
            s1 += __shfl_xor(s1, m);
            s2 += __shfl_xor(s2, m);
        }
        float mean = s1 * (1.f / 64.f);
        float var = s2 * (1.f / 64.f) - mean * mean;
        float rs = rsqrtf(var + 1e-5f);
#pragma unroll
        for (int n = 0; n < 4; ++n) {
            int f = n * 16 + r16;
            float o = (z[n] - mean) * rs * g[f] + be[f];
            fdst[v * 64 + f] = f2b(fmaxf(o, 0.f));
        }
    }
}

// ---------------------------------------------------------------- cell_out MLP (round-3 scalar version, known good)
__global__ __launch_bounds__(256) void k_mlp(
    const bfr* __restrict__ cell, const bfr* __restrict__ emb,
    const float* __restrict__ W1, const float* __restrict__ b1,
    const float* __restrict__ W2, const float* __restrict__ b2,
    bfr* __restrict__ cout)
{
    __shared__ alignas(16) bfr A[64][76];     // [node][cell(64)|emb(8)]
    __shared__ alignas(16) bfr W1T[64][76];   // W1T[f][k], k<72
    __shared__ alignas(16) bfr W2T[64][68];   // W2T[f][k], k<64
    __shared__ alignas(16) bfr Hb[64][68];    // hidden
    int t = threadIdx.x;
    int base = blockIdx.x * 64;

    for (int idx = t; idx < 72 * 64; idx += 256) { int k = idx >> 6, f = idx & 63; W1T[f][k] = f2b(W1[idx]); }
    for (int idx = t; idx < 64 * 64; idx += 256) { int k = idx >> 6, f = idx & 63; W2T[f][k] = f2b(W2[idx]); }
    for (int idx = t; idx < 64 * 64; idx += 256) { A[idx >> 6][idx & 63] = cell[(size_t)base * 64 + idx]; }
    for (int idx = t; idx < 64 * 8;  idx += 256) { A[idx >> 3][64 + (idx & 7)] = emb[(size_t)base * 8 + idx]; }
    __syncthreads();

    int tr = t >> 4, tc = t & 15;
    float y[4][4] = {};
    for (int k0 = 0; k0 < 72; k0 += 4) {
        float a[4][4], bb[4][4];
#pragma unroll
        for (int i = 0; i < 4; ++i) {
            ushort4 av = *(const ushort4*)&A[tr + 16 * i][k0];
            a[i][0] = b2f(av.x); a[i][1] = b2f(av.y); a[i][2] = b2f(av.z); a[i][3] = b2f(av.w);
        }
#pragma unroll
        for (int j = 0; j < 4; ++j) {
            ushort4 bv = *(const ushort4*)&W1T[tc + 16 * j][k0];
            bb[j][0] = b2f(bv.x); bb[j][1] = b2f(bv.y); bb[j][2] = b2f(bv.z); bb[j][3] = b2f(bv.w);
        }
#pragma unroll
        for (int i = 0; i < 4; ++i)
#pragma unroll
            for (int j = 0; j < 4; ++j) {
                y[i][j] = fmaf(a[i][0], bb[j][0], y[i][j]);
                y[i][j] = fmaf(a[i][1], bb[j][1], y[i][j]);
                y[i][j] = fmaf(a[i][2], bb[j][2], y[i][j]);
                y[i][j] = fmaf(a[i][3], bb[j][3], y[i][j]);
            }
    }
#pragma unroll
    for (int i = 0; i < 4; ++i)
#pragma unroll
        for (int j = 0; j < 4; ++j) {
            int f = tc + 16 * j;
            Hb[tr + 16 * i][f] = f2b(fmaxf(y[i][j] + b1[f], 0.f));
        }
    __syncthreads();

    float y2[4][4] = {};
    for (int k0 = 0; k0 < 64; k0 += 4) {
        float a[4][4], bb[4][4];
#pragma unroll
        for (int i = 0; i < 4; ++i) {
            ushort4 av = *(const ushort4*)&Hb[tr + 16 * i][k0];
            a[i][0] = b2f(av.x); a[i][1] = b2f(av.y); a[i][2] = b2f(av.z); a[i][3] = b2f(av.w);
        }
#pragma unroll
        for (int j = 0; j < 4; ++j) {
            ushort4 bv = *(const ushort4*)&W2T[tc + 16 * j][k0];
            bb[j][0] = b2f(bv.x); bb[j][1] = b2f(bv.y); bb[j][2] = b2f(bv.z); bb[j][3] = b2f(bv.w);
        }
#pragma unroll
        for (int i = 0; i < 4; ++i)
#pragma unroll
            for (int j = 0; j < 4; ++j) {
                y2[i][j] = fmaf(a[i][0], bb[j][0], y2[i][j]);
                y2[i][j] = fmaf(a[i][1], bb[j][1], y2[i][j]);
                y2[i][j] = fmaf(a[i][2], bb[j][2], y2[i][j]);
                y2[i][j] = fmaf(a[i][3], bb[j][3], y2[i][j]);
            }
    }
#pragma unroll
    for (int i = 0; i < 4; ++i)
#pragma unroll
        for (int j = 0; j < 4; ++j) {
            int f = tc + 16 * j;
            cout[(size_t)(base + tr + 16 * i) * 64 + f] = f2b(y2[i][j] + b2[f]);
        }
}

// ---------------------------------------------------------------- final projection (fp32 output)
__global__ void k_final(const bfr* __restrict__ net, const float* __restrict__ w,
                        const float* __restrict__ b, float* __restrict__ out, int n) {
    int gw = (blockIdx.x * blockDim.x + threadIdx.x) >> 6;
    int lane = threadIdx.x & 63;
    if (gw >= n) return;
    float p = b2f(net[gw * 64 + lane]) * w[lane];
    for (int m = 1; m < 64; m <<= 1) p += __shfl_xor(p, m);
    if (lane == 0) out[gw] = p + b[0];
}

// ---------------------------------------------------------------- launcher
extern "C" void kernel_launch(void* const* d_in, const int* in_sizes, int n_in,
                              void* d_out, int out_size, void* d_ws, size_t ws_size,
                              hipStream_t stream) {
    const float* net_x    = (const float*)d_in[0];
    const float* pin_in_x = (const float*)d_in[1];
    const float* pin_out_x= (const float*)d_in[2];
    const float* cell_x   = (const float*)d_in[3];
    const int* src1 = (const int*)d_in[4];
    const int* dst1 = (const int*)d_in[5];
    const int* src2 = (const int*)d_in[6];
    const int* dst2 = (const int*)d_in[7];
    const int* src3 = (const int*)d_in[8];
    const int* dst3 = (const int*)d_in[9];
    const int* src4 = (const int*)d_in[10];
    const int* dst4 = (const int*)d_in[11];
    const float* w_ct = (const float*)d_in[12];
    const float* b_ct = (const float*)d_in[13];
    const float* w_net = (const float*)d_in[14];
    const float* b_net = (const float*)d_in[15];
    const float* w_pi = (const float*)d_in[16];
    const float* b_pi = (const float*)d_in[17];
    const float* w_po = (const float*)d_in[18];
    const float* b_po = (const float*)d_in[19];
    const float* w_cs = (const float*)d_in[20];
    const float* b_cs = (const float*)d_in[21];
    const float* g_net = (const float*)d_in[22];
    const float* be_net = (const float*)d_in[23];
    const float* g_pi = (const float*)d_in[24];
    const float* be_pi = (const float*)d_in[25];
    const float* g_po = (const float*)d_in[26];
    const float* be_po = (const float*)d_in[27];
    const float* g_cell = (const float*)d_in[28];
    const float* be_cell = (const float*)d_in[29];
    const float* w_net_up = (const float*)d_in[30];
    const float* b_net_up = (const float*)d_in[31];
    const float* w_pi_up = (const float*)d_in[32];
    const float* b_pi_up = (const float*)d_in[33];
    const float* w_po_up = (const float*)d_in[34];
    const float* b_po_up = (const float*)d_in[35];
    const float* w_cell_up = (const float*)d_in[36];
    const float* b_cell_up = (const float*)d_in[37];
    const float* w_mlp1 = (const float*)d_in[38];
    const float* b_mlp1 = (const float*)d_in[39];
    const float* w_mlp2 = (const float*)d_in[40];
    const float* b_mlp2 = (const float*)d_in[41];
    const float* w_out = (const float*)d_in[42];
    const float* b_out = (const float*)d_in[43];

    size_t off = 0;
    auto take = [&](size_t bytes) {
        size_t c = off;
        off += (bytes + 255) & ~(size_t)255;
        return c;
    };
    char* ws = (char*)d_ws;
    bfr* f_net  = (bfr*)(ws + take((size_t)N_NETN * 64 * 2));
    bfr* f_pi   = (bfr*)(ws + take((size_t)N_PIN * 64 * 2));
    bfr* f_po   = (bfr*)(ws + take((size_t)N_PON * 64 * 2));
    bfr* f_cell = (bfr*)(ws + take((size_t)N_CELLN * 64 * 2));
    bfr* f_cout = (bfr*)(ws + take((size_t)N_CELLN * 64 * 2));
    bfr* f_emb  = (bfr*)(ws + take((size_t)N_CELLN * 8 * 2));
    int*   dcnt   = (int*)(ws + take((size_t)SRC_TOT * 4));
    float* invd   = (float*)dcnt;                 // aliased: in-place int->float
    int*   ccnt   = (int*)(ws + take((size_t)NT_DST * 4));
    int*   cursor = ccnt;                         // aliased: ccnt dead after scan
    int*   rp     = (int*)(ws + take((size_t)(NT_DST + 1) * 4));
    int*   col    = (int*)(ws + take((size_t)E_TOT * 4));
    int*   bsum   = (int*)(ws + take((size_t)NB_CHUNKS * 4));
    // pre-transposed bf16 weights (k_update only)
    bfr* wtb_pi   = (bfr*)(ws + take((size_t)64 * 192 * 2));
    bfr* wtb_cell = (bfr*)(ws + take((size_t)64 * 192 * 2));
    bfr* wtb_po   = (bfr*)(ws + take((size_t)64 * 192 * 2));
    bfr* wtb_net  = (bfr*)(ws + take((size_t)64 * 192 * 2));
    (void)in_sizes; (void)n_in; (void)out_size;

    if (ws_size < off) return;   // clean failure instead of memory fault

    dim3 B(256);
    auto cdiv = [](int a, int b) { return (a + b - 1) / b; };

    hipMemsetAsync(dcnt, 0, (size_t)SRC_TOT * 4, stream);
    hipMemsetAsync(ccnt, 0, (size_t)NT_DST * 4, stream);

    // weight prep (k_update weights only)
    k_prepw<<<cdiv(64 * 192, 256), B, 0, stream>>>(w_pi_up,   wtb_pi,   192, 64, 192);
    k_prepw<<<cdiv(64 * 192, 256), B, 0, stream>>>(w_cell_up, wtb_cell, 192, 64, 192);
    k_prepw<<<cdiv(64 * 192, 256), B, 0, stream>>>(w_po_up,   wtb_po,   192, 64, 192);
    k_prepw<<<cdiv(64 * 192, 256), B, 0, stream>>>(w_net_up,  wtb_net,  192, 64, 192);

    // source-degree histograms + reciprocals (in place)
    k_hist<<<cdiv(E1, 256), B, 0, stream>>>(src1, E1, dcnt + SB1);
    k_hist<<<cdiv(E2, 256), B, 0, stream>>>(src2, E2, dcnt + SB2);
    k_hist<<<cdiv(E3, 256), B, 0, stream>>>(src3, E3, dcnt + SB3);
    k_hist<<<cdiv(E4, 256), B, 0, stream>>>(src4, E4, dcnt + SB4);
    k_invdeg<<<cdiv(SRC_TOT, 256), B, 0, stream>>>(dcnt, invd, SRC_TOT);

    // dst histograms -> CSR row_ptr
    k_hist<<<cdiv(E1, 256), B, 0, stream>>>(dst1, E1, ccnt + PB_PI);
    k_hist<<<cdiv(E2, 256), B, 0, stream>>>(dst2, E2, ccnt + PB_CELL);
    k_hist<<<cdiv(E3, 256), B, 0, stream>>>(dst3, E3, ccnt + PB_PO);
    k_hist<<<cdiv(E4, 256), B, 0, stream>>>(dst4, E4, ccnt + PB_NET);
    k_scanA<<<NB_CHUNKS, B, 0, stream>>>(ccnt, NT_DST, bsum);
    k_scanB<<<1, B, 0, stream>>>(bsum, NB_CHUNKS);
    k_scanC<<<NB_CHUNKS, B, 0, stream>>>(ccnt, NT_DST, bsum, rp);
    k_copy<<<cdiv(NT_DST, 256), B, 0, stream>>>(rp, cursor, NT_DST);
    k_fill<<<cdiv(E1, 256), B, 0, stream>>>(src1, dst1, E1, PB_PI, cursor, col);
    k_fill<<<cdiv(E2, 256), B, 0, stream>>>(src2, dst2, E2, PB_CELL, cursor, col);
    k_fill<<<cdiv(E3, 256), B, 0, stream>>>(src3, dst3, E3, PB_PO, cursor, col);
    k_fill<<<cdiv(E4, 256), B, 0, stream>>>(src4, dst4, E4, PB_NET, cursor, col);

    // initial embeddings
    k_init_net<<<cdiv(N_NETN * 64, 256), B, 0, stream>>>(net_x, w_net, b_net, f_net, N_NETN);
    k_init_p3<<<cdiv(N_PIN * 64, 256), B, 0, stream>>>(pin_in_x, w_pi, b_pi, f_pi, N_PIN);
    k_init_p3<<<cdiv(N_PON * 64, 256), B, 0, stream>>>(pin_out_x, w_po, b_po, f_po, N_PON);
    k_init_cell<<<cdiv(N_CELLN * 64, 256), B, 0, stream>>>(cell_x, w_cs, b_cs, w_ct, b_ct,
                                                           f_cell, f_emb, N_CELLN);

    for (int l = 0; l < 4; ++l) {
        k_update<<<cdiv(N_PIN, 64), B, 0, stream>>>(
            N_PIN, f_pi, f_net, rp + PB_PI, col, invd + SB1, wtb_pi, b_pi_up, g_pi, be_pi);
        k_update<<<cdiv(N_CELLN, 64), B, 0, stream>>>(
            N_CELLN, f_cell, f_pi, rp + PB_CELL, col, invd + SB2, wtb_cell, b_cell_up, g_cell, be_cell);
        k_mlp<<<N_CELLN / 64, B, 0, stream>>>(f_cell, f_emb, w_mlp1, b_mlp1, w_mlp2, b_mlp2, f_cout);
        k_update<<<cdiv(N_PON, 64), B, 0, stream>>>(
            N_PON, f_po, f_cout, rp + PB_PO, col, invd + SB3, wtb_po, b_po_up, g_po, be_po);
        k_update<<<cdiv(N_NETN, 64), B, 0, stream>>>(
            N_NETN, f_net, f_po, rp + PB_NET, col, invd + SB4, wtb_net, b_net_up, g_net, be_net);
    }

    k_final<<<cdiv(N_NETN * 64, 256), B, 0, stream>>>(f_net, w_out, b_out, (float*)d_out, N_NETN);
}

// Round 9
// 2824.327 us; speedup vs baseline: 1.3444x; 1.2865x over previous
//
#include <hip/hip_runtime.h>
#include <cfloat>

#define HD 64
#define N_NETN 100000
#define N_PIN  400000
#define N_PON  200000
#define N_CELLN 200000
#define E1 400000
#define E2 400000
#define E3 200000
#define E4 200000
#define E_TOT (E1+E2+E3+E4)

#define PB_PI 0
#define PB_CELL (N_PIN)
#define PB_PO (N_PIN + N_CELLN)
#define PB_NET (N_PIN + N_CELLN + N_PON)
#define NT_DST (N_PIN + N_CELLN + N_PON + N_NETN)   // 900000

#define SB1 0
#define SB2 (N_NETN)
#define SB3 (N_NETN + N_PIN)
#define SB4 (N_NETN + N_PIN + N_CELLN)
#define SRC_TOT (N_NETN + N_PIN + N_CELLN + N_PON)  // 900000

#define SCAN_CHUNK 4096
#define NB_CHUNKS ((NT_DST + SCAN_CHUNK - 1) / SCAN_CHUNK)  // 220 (<=256)

typedef unsigned short bfr;  // raw bf16 storage
typedef __attribute__((ext_vector_type(8))) short sh8;    // staging copies
typedef __attribute__((ext_vector_type(4))) short sh4;    // 16x16x16 MFMA A/B frag (4 bf16)
typedef __attribute__((ext_vector_type(4))) float f32x4;  // MFMA C/D frag

// 16x16x16 bf16 MFMA: gfx90a-era layout, fully documented:
// A: lane l holds A[row=l&15][k=4*(l>>4)+i]; B mirrored; D: lane l reg i = D[4*(l>>4)+i][l&15]
#if __has_builtin(__builtin_amdgcn_mfma_f32_16x16x16bf16_1k)
#define MFMA16(a, b, c) __builtin_amdgcn_mfma_f32_16x16x16bf16_1k(a, b, c, 0, 0, 0)
#define HAVE_MFMA16 1
#elif __has_builtin(__builtin_amdgcn_mfma_f32_16x16x16_bf16)
#define MFMA16(a, b, c) __builtin_amdgcn_mfma_f32_16x16x16_bf16(a, b, c, 0, 0, 0)
#define HAVE_MFMA16 1
#else
#define HAVE_MFMA16 0
#endif

__device__ __forceinline__ float b2f(bfr u) {
    return __uint_as_float(((unsigned)u) << 16);
}
__device__ __forceinline__ bfr f2b(float f) {
    unsigned u = __float_as_uint(f);
    unsigned r = (u + 0x7FFFu + ((u >> 16) & 1u)) >> 16;   // RNE
    return (bfr)r;
}

// ---------------------------------------------------------------- histograms
__global__ void k_hist(const int* __restrict__ idx, int n, int* __restrict__ cnt) {
    int i = blockIdx.x * blockDim.x + threadIdx.x;
    if (i < n) atomicAdd(&cnt[idx[i]], 1);
}

__global__ void k_invdeg(const int* cnt, float* inv, int n) {
    int i = blockIdx.x * blockDim.x + threadIdx.x;
    if (i < n) {
        int c = cnt[i];
        inv[i] = 1.0f / (float)max(c, 1);
    }
}

// ---------------------------------------------------------------- scan
__global__ void k_scanA(const int* __restrict__ in, int n, int* __restrict__ bsum) {
    __shared__ int sh[256];
    int t = threadIdx.x, b = blockIdx.x;
    int base = b * SCAN_CHUNK + t * 16;
    int s = 0;
#pragma unroll
    for (int u = 0; u < 16; ++u) { int i = base + u; s += (i < n) ? in[i] : 0; }
    sh[t] = s; __syncthreads();
    for (int off = 128; off > 0; off >>= 1) { if (t < off) sh[t] += sh[t + off]; __syncthreads(); }
    if (t == 0) bsum[b] = sh[0];
}

__global__ void k_scanB(int* __restrict__ bsum, int nb) {
    __shared__ int sh[256];
    int t = threadIdx.x;
    int v = (t < nb) ? bsum[t] : 0;
    sh[t] = v; __syncthreads();
    for (int off = 1; off < 256; off <<= 1) {
        int add = (t >= off) ? sh[t - off] : 0;
        __syncthreads();
        sh[t] += add;
        __syncthreads();
    }
    if (t < nb) bsum[t] = sh[t] - v;  // exclusive
}

__global__ void k_scanC(const int* __restrict__ in, int n, const int* __restrict__ bsum,
                        int* __restrict__ rp) {
    __shared__ int sh[256];
    int t = threadIdx.x, b = blockIdx.x;
    int base = b * SCAN_CHUNK + t * 16;
    int x[16]; int s = 0;
#pragma unroll
    for (int u = 0; u < 16; ++u) { int i = base + u; x[u] = (i < n) ? in[i] : 0; s += x[u]; }
    sh[t] = s; __syncthreads();
    int mine = s;
    for (int off = 1; off < 256; off <<= 1) {
        int add = (t >= off) ? sh[t - off] : 0;
        __syncthreads();
        sh[t] += add;
        __syncthreads();
    }
    int run = bsum[b] + sh[t] - mine;
#pragma unroll
    for (int u = 0; u < 16; ++u) { int i = base + u; if (i < n) rp[i] = run; run += x[u]; }
    if (b == 0 && t == 0) rp[n] = E_TOT;
}

__global__ void k_fill(const int* __restrict__ src, const int* __restrict__ dst, int n,
                       int node_base, int* __restrict__ cursor, int* __restrict__ col) {
    int i = blockIdx.x * blockDim.x + threadIdx.x;
    if (i < n) {
        int p = atomicAdd(&cursor[node_base + dst[i]], 1);
        col[p] = src[i];
    }
}

__global__ void k_copy(const int* __restrict__ a, int* __restrict__ b, int n) {
    int i = blockIdx.x * blockDim.x + threadIdx.x;
    if (i < n) b[i] = a[i];
}

// ---------------------------------------------------------------- weight prep: fp32 [K][F] -> bf16 [F][ldout] transposed, zero-padded
__global__ void k_prepw(const float* __restrict__ w, bfr* __restrict__ out, int K, int F, int ldout) {
    int i = blockIdx.x * blockDim.x + threadIdx.x;
    int f = i / ldout, k = i - f * ldout;
    if (f < F) out[i] = (k < K) ? f2b(w[k * F + f]) : (bfr)0;
}

// ---------------------------------------------------------------- init embeddings (bf16 storage)
__global__ void k_init_net(const float* __restrict__ x, const float* __restrict__ w,
                           const float* __restrict__ b, bfr* __restrict__ out, int n) {
    int gw = (blockIdx.x * blockDim.x + threadIdx.x) >> 6;
    int lane = threadIdx.x & 63;
    if (gw >= n) return;
    float w0 = w[lane], w1 = w[64 + lane], w2 = w[128 + lane], w3 = w[192 + lane];
    float4 xv = ((const float4*)x)[gw];
    float y = b[lane];
    y = fmaf(xv.x, w0, y); y = fmaf(xv.y, w1, y); y = fmaf(xv.z, w2, y); y = fmaf(xv.w, w3, y);
    out[gw * 64 + lane] = f2b(fmaxf(y, 0.f));
}

__global__ void k_init_p3(const float* __restrict__ x, const float* __restrict__ w,
                          const float* __restrict__ b, bfr* __restrict__ out, int n) {
    int gw = (blockIdx.x * blockDim.x + threadIdx.x) >> 6;
    int lane = threadIdx.x & 63;
    if (gw >= n) return;
    float y = b[lane];
    y = fmaf(x[gw * 3 + 0], w[lane], y);
    y = fmaf(x[gw * 3 + 1], w[64 + lane], y);
    y = fmaf(x[gw * 3 + 2], w[128 + lane], y);
    out[gw * 64 + lane] = f2b(fmaxf(y, 0.f));
}

__global__ void k_init_cell(const float* __restrict__ cx, const float* __restrict__ wcs,
                            const float* __restrict__ bcs, const float* __restrict__ wct,
                            const float* __restrict__ bct, bfr* __restrict__ cell,
                            bfr* __restrict__ emb, int n) {
    int gw = (blockIdx.x * blockDim.x + threadIdx.x) >> 6;
    int lane = threadIdx.x & 63;
    if (gw >= n) return;
    const float* row = cx + (size_t)gw * 32;
    float y = bcs[lane];
#pragma unroll
    for (int k = 0; k < 6; ++k) y = fmaf(row[26 + k], wcs[k * 64 + lane], y);
    cell[gw * 64 + lane] = f2b(fmaxf(y, 0.f));
    if (lane < 8) {
        float e = bct[lane];
#pragma unroll
        for (int k = 0; k < 26; ++k) e = fmaf(row[k], wct[k * 8 + lane], e);
        emb[gw * 8 + lane] = f2b(e);
    }
}

// ---------------------------------------------------------------- fused stage: aggregate + MFMA(16x16x16) GEMM + LN + ReLU
// Epilogue mapping verified by round-7 scalar emulation:
// acc[n][j] -> node v = wave*16 + kb*4 + j, feature f = n*16 + r16.
__global__ __launch_bounds__(256) void k_update(
    int n_dst, bfr* __restrict__ fdst, const bfr* __restrict__ fsrc,
    const int* __restrict__ rp, const int* __restrict__ col,
    const float* __restrict__ invdeg, const bfr* __restrict__ wtb,
    const float* __restrict__ bup, const float* __restrict__ g, const float* __restrict__ be)
{
    __shared__ alignas(16) bfr WT[64][200];    // WT[f][k] = W[k][f] bf16, k<192
    __shared__ alignas(16) bfr comb[64][200];  // [node][ mean(64) | max(64) | min(64) ]
    int t = threadIdx.x;
    int tileBase = blockIdx.x * 64;
    int wave = t >> 6, lane = t & 63;

    // stage pre-transposed bf16 weights: 64 rows x 24 chunks of 8 = 1536 chunks
#pragma unroll
    for (int it = 0; it < 6; ++it) {
        int chunk = t + it * 256;
        int f = chunk / 24, kc = (chunk - f * 24) * 8;
        *(sh8*)&WT[f][kc] = ((const sh8*)wtb)[chunk];
    }

    // aggregation: wave handles 16 nodes, lane = feature
    for (int jj = 0; jj < 16; ++jj) {
        int nl = wave * 16 + jj;
        int v = tileBase + nl;
        float acc = 0.f, mx = -FLT_MAX, mn = FLT_MAX;
        int cnt = 0;
        if (v < n_dst) {
            int e0 = rp[v], e1 = rp[v + 1];
            cnt = e1 - e0;
            for (int e = e0; e < e1; ++e) {
                int s = col[e];
                float wg = invdeg[s];
                float xv = b2f(fsrc[s * 64 + lane]);
                acc = fmaf(wg, xv, acc);
                mx = fmaxf(mx, xv);
                mn = fminf(mn, xv);
            }
        }
        if (cnt == 0) { mx = 0.f; mn = 0.f; }
        comb[nl][lane] = f2b(acc);
        comb[nl][64 + lane] = f2b(mx);
        comb[nl][128 + lane] = f2b(mn);
    }
    __syncthreads();

    int r16 = lane & 15, kb = lane >> 4;

#if HAVE_MFMA16
    // 16x16x16 MFMA: A-frag = comb[row=r16][4 contig k at 4*kb], B-frag = WT[col][same].
    f32x4 acc[4];
#pragma unroll
    for (int n = 0; n < 4; ++n) acc[n] = (f32x4){0.f, 0.f, 0.f, 0.f};
#pragma unroll
    for (int ks = 0; ks < 12; ++ks) {
        sh4 af = *(const sh4*)&comb[wave * 16 + r16][ks * 16 + kb * 4];
#pragma unroll
        for (int n = 0; n < 4; ++n) {
            sh4 bf = *(const sh4*)&WT[n * 16 + r16][ks * 16 + kb * 4];
            acc[n] = MFMA16(af, bf, acc[n]);
        }
    }
#else
    // scalar fallback (round-7 verified path)
    float acc[4][4];
#pragma unroll
    for (int n = 0; n < 4; ++n)
#pragma unroll
        for (int j = 0; j < 4; ++j) acc[n][j] = 0.f;
    for (int k = 0; k < 192; ++k) {
        float bv[4];
#pragma unroll
        for (int n = 0; n < 4; ++n) bv[n] = b2f(WT[n * 16 + r16][k]);
#pragma unroll
        for (int j = 0; j < 4; ++j) {
            float a = b2f(comb[wave * 16 + kb * 4 + j][k]);
#pragma unroll
            for (int n = 0; n < 4; ++n) acc[n][j] = fmaf(a, bv[n], acc[n][j]);
        }
    }
#endif

    // epilogue: row = wave*16 + kb*4 + j, col = n*16 + r16 (round-7 verified)
#pragma unroll
    for (int j = 0; j < 4; ++j) {
        int v = tileBase + wave * 16 + kb * 4 + j;   // uniform across 16-lane shuffle group
        if (v >= n_dst) continue;
        float z[4], s1 = 0.f, s2 = 0.f;
#pragma unroll
        for (int n = 0; n < 4; ++n) {
            int f = n * 16 + r16;
            z[n] = b2f(fdst[v * 64 + f]) + acc[n][j] + bup[f];
            s1 += z[n];
            s2 += z[n] * z[n];
        }
        for (int m = 1; m < 16; m <<= 1) {
            s1 += __shfl_xor(s1, m);
            s2 += __shfl_xor(s2, m);
        }
        float mean = s1 * (1.f / 64.f);
        float var = s2 * (1.f / 64.f) - mean * mean;
        float rs = rsqrtf(var + 1e-5f);
#pragma unroll
        for (int n = 0; n < 4; ++n) {
            int f = n * 16 + r16;
            float o = (z[n] - mean) * rs * g[f] + be[f];
            fdst[v * 64 + f] = f2b(fmaxf(o, 0.f));
        }
    }
}

// ---------------------------------------------------------------- cell_out MLP (round-3 scalar version, known good)
__global__ __launch_bounds__(256) void k_mlp(
    const bfr* __restrict__ cell, const bfr* __restrict__ emb,
    const float* __restrict__ W1, const float* __restrict__ b1,
    const float* __restrict__ W2, const float* __restrict__ b2,
    bfr* __restrict__ cout)
{
    __shared__ alignas(16) bfr A[64][76];     // [node][cell(64)|emb(8)]
    __shared__ alignas(16) bfr W1T[64][76];   // W1T[f][k], k<72
    __shared__ alignas(16) bfr W2T[64][68];   // W2T[f][k], k<64
    __shared__ alignas(16) bfr Hb[64][68];    // hidden
    int t = threadIdx.x;
    int base = blockIdx.x * 64;

    for (int idx = t; idx < 72 * 64; idx += 256) { int k = idx >> 6, f = idx & 63; W1T[f][k] = f2b(W1[idx]); }
    for (int idx = t; idx < 64 * 64; idx += 256) { int k = idx >> 6, f = idx & 63; W2T[f][k] = f2b(W2[idx]); }
    for (int idx = t; idx < 64 * 64; idx += 256) { A[idx >> 6][idx & 63] = cell[(size_t)base * 64 + idx]; }
    for (int idx = t; idx < 64 * 8;  idx += 256) { A[idx >> 3][64 + (idx & 7)] = emb[(size_t)base * 8 + idx]; }
    __syncthreads();

    int tr = t >> 4, tc = t & 15;
    float y[4][4] = {};
    for (int k0 = 0; k0 < 72; k0 += 4) {
        float a[4][4], bb[4][4];
#pragma unroll
        for (int i = 0; i < 4; ++i) {
            ushort4 av = *(const ushort4*)&A[tr + 16 * i][k0];
            a[i][0] = b2f(av.x); a[i][1] = b2f(av.y); a[i][2] = b2f(av.z); a[i][3] = b2f(av.w);
        }
#pragma unroll
        for (int j = 0; j < 4; ++j) {
            ushort4 bv = *(const ushort4*)&W1T[tc + 16 * j][k0];
            bb[j][0] = b2f(bv.x); bb[j][1] = b2f(bv.y); bb[j][2] = b2f(bv.z); bb[j][3] = b2f(bv.w);
        }
#pragma unroll
        for (int i = 0; i < 4; ++i)
#pragma unroll
            for (int j = 0; j < 4; ++j) {
                y[i][j] = fmaf(a[i][0], bb[j][0], y[i][j]);
                y[i][j] = fmaf(a[i][1], bb[j][1], y[i][j]);
                y[i][j] = fmaf(a[i][2], bb[j][2], y[i][j]);
                y[i][j] = fmaf(a[i][3], bb[j][3], y[i][j]);
            }
    }
#pragma unroll
    for (int i = 0; i < 4; ++i)
#pragma unroll
        for (int j = 0; j < 4; ++j) {
            int f = tc + 16 * j;
            Hb[tr + 16 * i][f] = f2b(fmaxf(y[i][j] + b1[f], 0.f));
        }
    __syncthreads();

    float y2[4][4] = {};
    for (int k0 = 0; k0 < 64; k0 += 4) {
        float a[4][4], bb[4][4];
#pragma unroll
        for (int i = 0; i < 4; ++i) {
            ushort4 av = *(const ushort4*)&Hb[tr + 16 * i][k0];
            a[i][0] = b2f(av.x); a[i][1] = b2f(av.y); a[i][2] = b2f(av.z); a[i][3] = b2f(av.w);
        }
#pragma unroll
        for (int j = 0; j < 4; ++j) {
            ushort4 bv = *(const ushort4*)&W2T[tc + 16 * j][k0];
            bb[j][0] = b2f(bv.x); bb[j][1] = b2f(bv.y); bb[j][2] = b2f(bv.z); bb[j][3] = b2f(bv.w);
        }
#pragma unroll
        for (int i = 0; i < 4; ++i)
#pragma unroll
            for (int j = 0; j < 4; ++j) {
                y2[i][j] = fmaf(a[i][0], bb[j][0], y2[i][j]);
                y2[i][j] = fmaf(a[i][1], bb[j][1], y2[i][j]);
                y2[i][j] = fmaf(a[i][2], bb[j][2], y2[i][j]);
                y2[i][j] = fmaf(a[i][3], bb[j][3], y2[i][j]);
            }
    }
#pragma unroll
    for (int i = 0; i < 4; ++i)
#pragma unroll
        for (int j = 0; j < 4; ++j) {
            int f = tc + 16 * j;
            cout[(size_t)(base + tr + 16 * i) * 64 + f] = f2b(y2[i][j] + b2[f]);
        }
}

// ---------------------------------------------------------------- final projection (fp32 output)
__global__ void k_final(const bfr* __restrict__ net, const float* __restrict__ w,
                        const float* __restrict__ b, float* __restrict__ out, int n) {
    int gw = (blockIdx.x * blockDim.x + threadIdx.x) >> 6;
    int lane = threadIdx.x & 63;
    if (gw >= n) return;
    float p = b2f(net[gw * 64 + lane]) * w[lane];
    for (int m = 1; m < 64; m <<= 1) p += __shfl_xor(p, m);
    if (lane == 0) out[gw] = p + b[0];
}

// ---------------------------------------------------------------- launcher
extern "C" void kernel_launch(void* const* d_in, const int* in_sizes, int n_in,
                              void* d_out, int out_size, void* d_ws, size_t ws_size,
                              hipStream_t stream) {
    const float* net_x    = (const float*)d_in[0];
    const float* pin_in_x = (const float*)d_in[1];
    const float* pin_out_x= (const float*)d_in[2];
    const float* cell_x   = (const float*)d_in[3];
    const int* src1 = (const int*)d_in[4];
    const int* dst1 = (const int*)d_in[5];
    const int* src2 = (const int*)d_in[6];
    const int* dst2 = (const int*)d_in[7];
    const int* src3 = (const int*)d_in[8];
    const int* dst3 = (const int*)d_in[9];
    const int* src4 = (const int*)d_in[10];
    const int* dst4 = (const int*)d_in[11];
    const float* w_ct = (const float*)d_in[12];
    const float* b_ct = (const float*)d_in[13];
    const float* w_net = (const float*)d_in[14];
    const float* b_net = (const float*)d_in[15];
    const float* w_pi = (const float*)d_in[16];
    const float* b_pi = (const float*)d_in[17];
    const float* w_po = (const float*)d_in[18];
    const float* b_po = (const float*)d_in[19];
    const float* w_cs = (const float*)d_in[20];
    const float* b_cs = (const float*)d_in[21];
    const float* g_net = (const float*)d_in[22];
    const float* be_net = (const float*)d_in[23];
    const float* g_pi = (const float*)d_in[24];
    const float* be_pi = (const float*)d_in[25];
    const float* g_po = (const float*)d_in[26];
    const float* be_po = (const float*)d_in[27];
    const float* g_cell = (const float*)d_in[28];
    const float* be_cell = (const float*)d_in[29];
    const float* w_net_up = (const float*)d_in[30];
    const float* b_net_up = (const float*)d_in[31];
    const float* w_pi_up = (const float*)d_in[32];
    const float* b_pi_up = (const float*)d_in[33];
    const float* w_po_up = (const float*)d_in[34];
    const float* b_po_up = (const float*)d_in[35];
    const float* w_cell_up = (const float*)d_in[36];
    const float* b_cell_up = (const float*)d_in[37];
    const float* w_mlp1 = (const float*)d_in[38];
    const float* b_mlp1 = (const float*)d_in[39];
    const float* w_mlp2 = (const float*)d_in[40];
    const float* b_mlp2 = (const float*)d_in[41];
    const float* w_out = (const float*)d_in[42];
    const float* b_out = (const float*)d_in[43];

    size_t off = 0;
    auto take = [&](size_t bytes) {
        size_t c = off;
        off += (bytes + 255) & ~(size_t)255;
        return c;
    };
    char* ws = (char*)d_ws;
    bfr* f_net  = (bfr*)(ws + take((size_t)N_NETN * 64 * 2));
    bfr* f_pi   = (bfr*)(ws + take((size_t)N_PIN * 64 * 2));
    bfr* f_po   = (bfr*)(ws + take((size_t)N_PON * 64 * 2));
    bfr* f_cell = (bfr*)(ws + take((size_t)N_CELLN * 64 * 2));
    bfr* f_cout = (bfr*)(ws + take((size_t)N_CELLN * 64 * 2));
    bfr* f_emb  = (bfr*)(ws + take((size_t)N_CELLN * 8 * 2));
    int*   dcnt   = (int*)(ws + take((size_t)SRC_TOT * 4));
    float* invd   = (float*)dcnt;                 // aliased: in-place int->float
    int*   ccnt   = (int*)(ws + take((size_t)NT_DST * 4));
    int*   cursor = ccnt;                         // aliased: ccnt dead after scan
    int*   rp     = (int*)(ws + take((size_t)(NT_DST + 1) * 4));
    int*   col    = (int*)(ws + take((size_t)E_TOT * 4));
    int*   bsum   = (int*)(ws + take((size_t)NB_CHUNKS * 4));
    // pre-transposed bf16 weights (k_update only)
    bfr* wtb_pi   = (bfr*)(ws + take((size_t)64 * 192 * 2));
    bfr* wtb_cell = (bfr*)(ws + take((size_t)64 * 192 * 2));
    bfr* wtb_po   = (bfr*)(ws + take((size_t)64 * 192 * 2));
    bfr* wtb_net  = (bfr*)(ws + take((size_t)64 * 192 * 2));
    (void)in_sizes; (void)n_in; (void)out_size;

    if (ws_size < off) return;   // clean failure instead of memory fault

    dim3 B(256);
    auto cdiv = [](int a, int b) { return (a + b - 1) / b; };

    hipMemsetAsync(dcnt, 0, (size_t)SRC_TOT * 4, stream);
    hipMemsetAsync(ccnt, 0, (size_t)NT_DST * 4, stream);

    // weight prep (k_update weights only)
    k_prepw<<<cdiv(64 * 192, 256), B, 0, stream>>>(w_pi_up,   wtb_pi,   192, 64, 192);
    k_prepw<<<cdiv(64 * 192, 256), B, 0, stream>>>(w_cell_up, wtb_cell, 192, 64, 192);
    k_prepw<<<cdiv(64 * 192, 256), B, 0, stream>>>(w_po_up,   wtb_po,   192, 64, 192);
    k_prepw<<<cdiv(64 * 192, 256), B, 0, stream>>>(w_net_up,  wtb_net,  192, 64, 192);

    // source-degree histograms + reciprocals (in place)
    k_hist<<<cdiv(E1, 256), B, 0, stream>>>(src1, E1, dcnt + SB1);
    k_hist<<<cdiv(E2, 256), B, 0, stream>>>(src2, E2, dcnt + SB2);
    k_hist<<<cdiv(E3, 256), B, 0, stream>>>(src3, E3, dcnt + SB3);
    k_hist<<<cdiv(E4, 256), B, 0, stream>>>(src4, E4, dcnt + SB4);
    k_invdeg<<<cdiv(SRC_TOT, 256), B, 0, stream>>>(dcnt, invd, SRC_TOT);

    // dst histograms -> CSR row_ptr
    k_hist<<<cdiv(E1, 256), B, 0, stream>>>(dst1, E1, ccnt + PB_PI);
    k_hist<<<cdiv(E2, 256), B, 0, stream>>>(dst2, E2, ccnt + PB_CELL);
    k_hist<<<cdiv(E3, 256), B, 0, stream>>>(dst3, E3, ccnt + PB_PO);
    k_hist<<<cdiv(E4, 256), B, 0, stream>>>(dst4, E4, ccnt + PB_NET);
    k_scanA<<<NB_CHUNKS, B, 0, stream>>>(ccnt, NT_DST, bsum);
    k_scanB<<<1, B, 0, stream>>>(bsum, NB_CHUNKS);
    k_scanC<<<NB_CHUNKS, B, 0, stream>>>(ccnt, NT_DST, bsum, rp);
    k_copy<<<cdiv(NT_DST, 256), B, 0, stream>>>(rp, cursor, NT_DST);
    k_fill<<<cdiv(E1, 256), B, 0, stream>>>(src1, dst1, E1, PB_PI, cursor, col);
    k_fill<<<cdiv(E2, 256), B, 0, stream>>>(src2, dst2, E2, PB_CELL, cursor, col);
    k_fill<<<cdiv(E3, 256), B, 0, stream>>>(src3, dst3, E3, PB_PO, cursor, col);
    k_fill<<<cdiv(E4, 256), B, 0, stream>>>(src4, dst4, E4, PB_NET, cursor, col);

    // initial embeddings
    k_init_net<<<cdiv(N_NETN * 64, 256), B, 0, stream>>>(net_x, w_net, b_net, f_net, N_NETN);
    k_init_p3<<<cdiv(N_PIN * 64, 256), B, 0, stream>>>(pin_in_x, w_pi, b_pi, f_pi, N_PIN);
    k_init_p3<<<cdiv(N_PON * 64, 256), B, 0, stream>>>(pin_out_x, w_po, b_po, f_po, N_PON);
    k_init_cell<<<cdiv(N_CELLN * 64, 256), B, 0, stream>>>(cell_x, w_cs, b_cs, w_ct, b_ct,
                                                           f_cell, f_emb, N_CELLN);

    for (int l = 0; l < 4; ++l) {
        k_update<<<cdiv(N_PIN, 64), B, 0, stream>>>(
            N_PIN, f_pi, f_net, rp + PB_PI, col, invd + SB1, wtb_pi, b_pi_up, g_pi, be_pi);
        k_update<<<cdiv(N_CELLN, 64), B, 0, stream>>>(
            N_CELLN, f_cell, f_pi, rp + PB_CELL, col, invd + SB2, wtb_cell, b_cell_up, g_cell, be_cell);
        k_mlp<<<N_CELLN / 64, B, 0, stream>>>(f_cell, f_emb, w_mlp1, b_mlp1, w_mlp2, b_mlp2, f_cout);
        k_update<<<cdiv(N_PON, 64), B, 0, stream>>>(
            N_PON, f_po, f_cout, rp + PB_PO, col, invd + SB3, wtb_po, b_po_up, g_po, be_po);
        k_update<<<cdiv(N_NETN, 64), B, 0, stream>>>(
            N_NETN, f_net, f_po, rp + PB_NET, col, invd + SB4, wtb_net, b_net_up, g_net, be_net);
    }

    k_final<<<cdiv(N_NETN * 64, 256), B, 0, stream>>>(f_net, w_out, b_out, (float*)d_out, N_NETN);
}

// Round 11
// 1468.018 us; speedup vs baseline: 2.5865x; 1.9239x over previous
//
#include <hip/hip_runtime.h>
#include <cfloat>

#define HD 64
#define N_NETN 100000
#define N_PIN  400000
#define N_PON  200000
#define N_CELLN 200000
#define E1 400000
#define E2 400000
#define E3 200000
#define E4 200000
#define E_TOT (E1+E2+E3+E4)

#define PB_PI 0
#define PB_CELL (N_PIN)
#define PB_PO (N_PIN + N_CELLN)
#define PB_NET (N_PIN + N_CELLN + N_PON)
#define NT_DST (N_PIN + N_CELLN + N_PON + N_NETN)   // 900000

#define SB1 0
#define SB2 (N_NETN)
#define SB3 (N_NETN + N_PIN)
#define SB4 (N_NETN + N_PIN + N_CELLN)
#define SRC_TOT (N_NETN + N_PIN + N_CELLN + N_PON)  // 900000

#define SCAN_CHUNK 4096
#define NB_CHUNKS ((NT_DST + SCAN_CHUNK - 1) / SCAN_CHUNK)  // 220 (<=256)

typedef unsigned short bfr;  // raw bf16 storage
typedef __attribute__((ext_vector_type(8))) short sh8;    // staging copies / gather loads
typedef __attribute__((ext_vector_type(4))) short sh4;    // 16x16x16 MFMA A/B frag (4 bf16)
typedef __attribute__((ext_vector_type(4))) float f32x4;  // MFMA C/D frag

// 16x16x16 bf16 MFMA (verified on gfx950 in round 9):
// A: lane l holds A[row=l&15][k=4*(l>>4)+i]; B mirrored; D: lane l reg i = D[4*(l>>4)+i][l&15]
// NOTE: must keep a builtin-free #else branch — the HOST compile pass parses
// these bodies and has no amdgcn builtins (round-10 lesson).
#if __has_builtin(__builtin_amdgcn_mfma_f32_16x16x16bf16_1k)
#define MFMA16(a, b, c) __builtin_amdgcn_mfma_f32_16x16x16bf16_1k(a, b, c, 0, 0, 0)
#define HAVE_MFMA16 1
#elif __has_builtin(__builtin_amdgcn_mfma_f32_16x16x16_bf16)
#define MFMA16(a, b, c) __builtin_amdgcn_mfma_f32_16x16x16_bf16(a, b, c, 0, 0, 0)
#define HAVE_MFMA16 1
#else
#define HAVE_MFMA16 0
#endif

__device__ __forceinline__ float b2f(bfr u) {
    return __uint_as_float(((unsigned)u) << 16);
}
__device__ __forceinline__ bfr f2b(float f) {
    unsigned u = __float_as_uint(f);
    unsigned r = (u + 0x7FFFu + ((u >> 16) & 1u)) >> 16;   // RNE
    return (bfr)r;
}

// ---------------------------------------------------------------- histograms
__global__ void k_hist(const int* __restrict__ idx, int n, int* __restrict__ cnt) {
    int i = blockIdx.x * blockDim.x + threadIdx.x;
    if (i < n) atomicAdd(&cnt[idx[i]], 1);
}

__global__ void k_invdeg(const int* cnt, float* inv, int n) {
    int i = blockIdx.x * blockDim.x + threadIdx.x;
    if (i < n) {
        int c = cnt[i];
        inv[i] = 1.0f / (float)max(c, 1);
    }
}

// ---------------------------------------------------------------- scan
__global__ void k_scanA(const int* __restrict__ in, int n, int* __restrict__ bsum) {
    __shared__ int sh[256];
    int t = threadIdx.x, b = blockIdx.x;
    int base = b * SCAN_CHUNK + t * 16;
    int s = 0;
#pragma unroll
    for (int u = 0; u < 16; ++u) { int i = base + u; s += (i < n) ? in[i] : 0; }
    sh[t] = s; __syncthreads();
    for (int off = 128; off > 0; off >>= 1) { if (t < off) sh[t] += sh[t + off]; __syncthreads(); }
    if (t == 0) bsum[b] = sh[0];
}

__global__ void k_scanB(int* __restrict__ bsum, int nb) {
    __shared__ int sh[256];
    int t = threadIdx.x;
    int v = (t < nb) ? bsum[t] : 0;
    sh[t] = v; __syncthreads();
    for (int off = 1; off < 256; off <<= 1) {
        int add = (t >= off) ? sh[t - off] : 0;
        __syncthreads();
        sh[t] += add;
        __syncthreads();
    }
    if (t < nb) bsum[t] = sh[t] - v;  // exclusive
}

__global__ void k_scanC(const int* __restrict__ in, int n, const int* __restrict__ bsum,
                        int* __restrict__ rp) {
    __shared__ int sh[256];
    int t = threadIdx.x, b = blockIdx.x;
    int base = b * SCAN_CHUNK + t * 16;
    int x[16]; int s = 0;
#pragma unroll
    for (int u = 0; u < 16; ++u) { int i = base + u; x[u] = (i < n) ? in[i] : 0; s += x[u]; }
    sh[t] = s; __syncthreads();
    int mine = s;
    for (int off = 1; off < 256; off <<= 1) {
        int add = (t >= off) ? sh[t - off] : 0;
        __syncthreads();
        sh[t] += add;
        __syncthreads();
    }
    int run = bsum[b] + sh[t] - mine;
#pragma unroll
    for (int u = 0; u < 16; ++u) { int i = base + u; if (i < n) rp[i] = run; run += x[u]; }
    if (b == 0 && t == 0) rp[n] = E_TOT;
}

__global__ void k_fill(const int* __restrict__ src, const int* __restrict__ dst, int n,
                       int node_base, int* __restrict__ cursor, int* __restrict__ col) {
    int i = blockIdx.x * blockDim.x + threadIdx.x;
    if (i < n) {
        int p = atomicAdd(&cursor[node_base + dst[i]], 1);
        col[p] = src[i];
    }
}

__global__ void k_copy(const int* __restrict__ a, int* __restrict__ b, int n) {
    int i = blockIdx.x * blockDim.x + threadIdx.x;
    if (i < n) b[i] = a[i];
}

// ---------------------------------------------------------------- weight prep: fp32 [K][F] -> bf16 [F][ldout] transposed, zero-padded
__global__ void k_prepw(const float* __restrict__ w, bfr* __restrict__ out, int K, int F, int ldout) {
    int i = blockIdx.x * blockDim.x + threadIdx.x;
    int f = i / ldout, k = i - f * ldout;
    if (f < F) out[i] = (k < K) ? f2b(w[k * F + f]) : (bfr)0;
}

// ---------------------------------------------------------------- init embeddings (bf16 storage)
__global__ void k_init_net(const float* __restrict__ x, const float* __restrict__ w,
                           const float* __restrict__ b, bfr* __restrict__ out, int n) {
    int gw = (blockIdx.x * blockDim.x + threadIdx.x) >> 6;
    int lane = threadIdx.x & 63;
    if (gw >= n) return;
    float w0 = w[lane], w1 = w[64 + lane], w2 = w[128 + lane], w3 = w[192 + lane];
    float4 xv = ((const float4*)x)[gw];
    float y = b[lane];
    y = fmaf(xv.x, w0, y); y = fmaf(xv.y, w1, y); y = fmaf(xv.z, w2, y); y = fmaf(xv.w, w3, y);
    out[gw * 64 + lane] = f2b(fmaxf(y, 0.f));
}

__global__ void k_init_p3(const float* __restrict__ x, const float* __restrict__ w,
                          const float* __restrict__ b, bfr* __restrict__ out, int n) {
    int gw = (blockIdx.x * blockDim.x + threadIdx.x) >> 6;
    int lane = threadIdx.x & 63;
    if (gw >= n) return;
    float y = b[lane];
    y = fmaf(x[gw * 3 + 0], w[lane], y);
    y = fmaf(x[gw * 3 + 1], w[64 + lane], y);
    y = fmaf(x[gw * 3 + 2], w[128 + lane], y);
    out[gw * 64 + lane] = f2b(fmaxf(y, 0.f));
}

__global__ void k_init_cell(const float* __restrict__ cx, const float* __restrict__ wcs,
                            const float* __restrict__ bcs, const float* __restrict__ wct,
                            const float* __restrict__ bct, bfr* __restrict__ cell,
                            bfr* __restrict__ emb, int n) {
    int gw = (blockIdx.x * blockDim.x + threadIdx.x) >> 6;
    int lane = threadIdx.x & 63;
    if (gw >= n) return;
    const float* row = cx + (size_t)gw * 32;
    float y = bcs[lane];
#pragma unroll
    for (int k = 0; k < 6; ++k) y = fmaf(row[26 + k], wcs[k * 64 + lane], y);
    cell[gw * 64 + lane] = f2b(fmaxf(y, 0.f));
    if (lane < 8) {
        float e = bct[lane];
#pragma unroll
        for (int k = 0; k < 26; ++k) e = fmaf(row[k], wct[k * 8 + lane], e);
        emb[gw * 8 + lane] = f2b(e);
    }
}

// ---------------------------------------------------------------- fused stage: aggregate + MFMA(16x16x16) GEMM + LN + ReLU
// Node-parallel aggregation: thread group of 4 per node (16 features each, in
// registers) -> 64 concurrent gather chains per block. GEMM + epilogue
// byte-identical to the round-9 verified version.
__global__ __launch_bounds__(256) void k_update(
    int n_dst, bfr* __restrict__ fdst, const bfr* __restrict__ fsrc,
    const int* __restrict__ rp, const int* __restrict__ col,
    const float* __restrict__ invdeg, const bfr* __restrict__ wtb,
    const float* __restrict__ bup, const float* __restrict__ g, const float* __restrict__ be)
{
    __shared__ alignas(16) bfr WT[64][200];    // WT[f][k] = W[k][f] bf16, k<192
    __shared__ alignas(16) bfr comb[64][200];  // [node][ mean(64) | max(64) | min(64) ]
    int t = threadIdx.x;
    int tileBase = blockIdx.x * 64;
    int wave = t >> 6, lane = t & 63;

    // stage pre-transposed bf16 weights: 64 rows x 24 chunks of 8 = 1536 chunks
#pragma unroll
    for (int it = 0; it < 6; ++it) {
        int chunk = t + it * 256;
        int f = chunk / 24, kc = (chunk - f * 24) * 8;
        *(sh8*)&WT[f][kc] = ((const sh8*)wtb)[chunk];
    }

    // node-parallel aggregation: node nl = t>>2, features fq..fq+15 per thread
    {
        int nl = t >> 2;
        int fq = (t & 3) << 4;
        int v = tileBase + nl;
        float sum[16], mx[16], mn[16];
#pragma unroll
        for (int i = 0; i < 16; ++i) { sum[i] = 0.f; mx[i] = -FLT_MAX; mn[i] = FLT_MAX; }
        int cnt = 0;
        if (v < n_dst) {
            int e0 = rp[v], e1 = rp[v + 1];
            cnt = e1 - e0;
            for (int e = e0; e < e1; ++e) {
                int s = col[e];
                float wg = invdeg[s];
                const sh8* row = (const sh8*)&fsrc[(size_t)s * 64 + fq];
                sh8 x0 = row[0], x1 = row[1];
#pragma unroll
                for (int i = 0; i < 8; ++i) {
                    float a0 = b2f((bfr)x0[i]);
                    float a1 = b2f((bfr)x1[i]);
                    sum[i]     = fmaf(wg, a0, sum[i]);
                    mx[i]      = fmaxf(mx[i], a0);
                    mn[i]      = fminf(mn[i], a0);
                    sum[8 + i] = fmaf(wg, a1, sum[8 + i]);
                    mx[8 + i]  = fmaxf(mx[8 + i], a1);
                    mn[8 + i]  = fminf(mn[8 + i], a1);
                }
            }
        }
        if (cnt == 0) {
#pragma unroll
            for (int i = 0; i < 16; ++i) { mx[i] = 0.f; mn[i] = 0.f; }
        }
#pragma unroll
        for (int i = 0; i < 16; ++i) {
            comb[nl][fq + i]       = f2b(sum[i]);
            comb[nl][64 + fq + i]  = f2b(mx[i]);
            comb[nl][128 + fq + i] = f2b(mn[i]);
        }
    }
    __syncthreads();

    int r16 = lane & 15, kb = lane >> 4;

#if HAVE_MFMA16
    // 16x16x16 MFMA (round-9 verified): A = comb rows, B = WT rows, 12 k-steps
    f32x4 acc[4];
#pragma unroll
    for (int n = 0; n < 4; ++n) acc[n] = (f32x4){0.f, 0.f, 0.f, 0.f};
#pragma unroll
    for (int ks = 0; ks < 12; ++ks) {
        sh4 af = *(const sh4*)&comb[wave * 16 + r16][ks * 16 + kb * 4];
#pragma unroll
        for (int n = 0; n < 4; ++n) {
            sh4 bf = *(const sh4*)&WT[n * 16 + r16][ks * 16 + kb * 4];
            acc[n] = MFMA16(af, bf, acc[n]);
        }
    }
#else
    // scalar fallback (round-7 verified path; also keeps the HOST pass compiling)
    float acc[4][4];
#pragma unroll
    for (int n = 0; n < 4; ++n)
#pragma unroll
        for (int j = 0; j < 4; ++j) acc[n][j] = 0.f;
    for (int k = 0; k < 192; ++k) {
        float bv[4];
#pragma unroll
        for (int n = 0; n < 4; ++n) bv[n] = b2f(WT[n * 16 + r16][k]);
#pragma unroll
        for (int j = 0; j < 4; ++j) {
            float a = b2f(comb[wave * 16 + kb * 4 + j][k]);
#pragma unroll
            for (int n = 0; n < 4; ++n) acc[n][j] = fmaf(a, bv[n], acc[n][j]);
        }
    }
#endif

    // epilogue: row = wave*16 + kb*4 + j, col = n*16 + r16 (round-7/9 verified)
#pragma unroll
    for (int j = 0; j < 4; ++j) {
        int v = tileBase + wave * 16 + kb * 4 + j;   // uniform across 16-lane shuffle group
        if (v >= n_dst) continue;
        float z[4], s1 = 0.f, s2 = 0.f;
#pragma unroll
        for (int n = 0; n < 4; ++n) {
            int f = n * 16 + r16;
            z[n] = b2f(fdst[v * 64 + f]) + acc[n][j] + bup[f];
            s1 += z[n];
            s2 += z[n] * z[n];
        }
        for (int m = 1; m < 16; m <<= 1) {
            s1 += __shfl_xor(s1, m);
            s2 += __shfl_xor(s2, m);
        }
        float mean = s1 * (1.f / 64.f);
        float var = s2 * (1.f / 64.f) - mean * mean;
        float rs = rsqrtf(var + 1e-5f);
#pragma unroll
        for (int n = 0; n < 4; ++n) {
            int f = n * 16 + r16;
            float o = (z[n] - mean) * rs * g[f] + be[f];
            fdst[v * 64 + f] = f2b(fmaxf(o, 0.f));
        }
    }
}

// ---------------------------------------------------------------- cell_out MLP: two chained MFMA16 GEMMs (same verified mapping)
__global__ __launch_bounds__(256) void k_mlp(
    const bfr* __restrict__ cell, const bfr* __restrict__ emb,
    const bfr* __restrict__ w1b, const float* __restrict__ b1,
    const bfr* __restrict__ w2b, const float* __restrict__ b2,
    bfr* __restrict__ cout)
{
    __shared__ alignas(16) bfr A[64][104];    // [node][cell(64)|emb(8)|zeros(72..95)], stride 104
    __shared__ alignas(16) bfr W1T[64][104];  // prepped [f][k] ld 96, staged into stride 104
    __shared__ alignas(16) bfr W2T[64][72];   // prepped [f][k], ld 72 == stride -> flat copy
    __shared__ alignas(16) bfr Hb[64][72];    // hidden, stride 72
    int t = threadIdx.x, wave = t >> 6, lane = t & 63;
    int base = blockIdx.x * 64;
    int r16 = lane & 15, kb = lane >> 4;

    // W1T: 64 rows x 12 chunks (ld 96) -> stride 104
#pragma unroll
    for (int it = 0; it < 3; ++it) {
        int ch = t + it * 256;
        int f = ch / 12, kc = (ch - f * 12) * 8;
        *(sh8*)&W1T[f][kc] = ((const sh8*)w1b)[ch];
    }
    // W2T: flat copy 576 chunks (stride == ld == 72)
#pragma unroll
    for (int it = 0; it < 3; ++it) {
        int ch = t + it * 256;
        if (ch < 576) ((sh8*)W2T)[ch] = ((const sh8*)w2b)[ch];
    }
    // A: cell rows (512 chunks), emb col 64..71, zeros 72..95
#pragma unroll
    for (int it = 0; it < 2; ++it) {
        int ch = t + it * 256;
        int r = ch >> 3, c8 = (ch & 7) * 8;
        *(sh8*)&A[r][c8] = ((const sh8*)cell)[(size_t)base * 8 + ch];
    }
    if (t < 64) {
        *(sh8*)&A[t][64] = ((const sh8*)emb)[base + t];
        sh8 zz = (sh8){0, 0, 0, 0, 0, 0, 0, 0};
        *(sh8*)&A[t][72] = zz;
        *(sh8*)&A[t][80] = zz;
        *(sh8*)&A[t][88] = zz;
    }
    __syncthreads();

#if HAVE_MFMA16
    // GEMM1: K=96 (6 k-steps), relu(+b1) -> Hb
    f32x4 a1[4];
#pragma unroll
    for (int n = 0; n < 4; ++n) a1[n] = (f32x4){0.f, 0.f, 0.f, 0.f};
#pragma unroll
    for (int ks = 0; ks < 6; ++ks) {
        sh4 af = *(const sh4*)&A[wave * 16 + r16][ks * 16 + kb * 4];
#pragma unroll
        for (int n = 0; n < 4; ++n) {
            sh4 bf = *(const sh4*)&W1T[n * 16 + r16][ks * 16 + kb * 4];
            a1[n] = MFMA16(af, bf, a1[n]);
        }
    }
#else
    float a1[4][4];
#pragma unroll
    for (int n = 0; n < 4; ++n)
#pragma unroll
        for (int j = 0; j < 4; ++j) a1[n][j] = 0.f;
    for (int k = 0; k < 96; ++k) {
        float bv[4];
#pragma unroll
        for (int n = 0; n < 4; ++n) bv[n] = b2f(W1T[n * 16 + r16][k]);
#pragma unroll
        for (int j = 0; j < 4; ++j) {
            float a = b2f(A[wave * 16 + kb * 4 + j][k]);
#pragma unroll
            for (int n = 0; n < 4; ++n) a1[n][j] = fmaf(a, bv[n], a1[n][j]);
        }
    }
#endif
#pragma unroll
    for (int j = 0; j < 4; ++j)
#pragma unroll
        for (int n = 0; n < 4; ++n) {
            int f = n * 16 + r16;
            Hb[wave * 16 + kb * 4 + j][f] = f2b(fmaxf(a1[n][j] + b1[f], 0.f));
        }
    __syncthreads();

#if HAVE_MFMA16
    // GEMM2: K=64 (4 k-steps), +b2 -> cout
    f32x4 a2[4];
#pragma unroll
    for (int n = 0; n < 4; ++n) a2[n] = (f32x4){0.f, 0.f, 0.f, 0.f};
#pragma unroll
    for (int ks = 0; ks < 4; ++ks) {
        sh4 af = *(const sh4*)&Hb[wave * 16 + r16][ks * 16 + kb * 4];
#pragma unroll
        for (int n = 0; n < 4; ++n) {
            sh4 bf = *(const sh4*)&W2T[n * 16 + r16][ks * 16 + kb * 4];
            a2[n] = MFMA16(af, bf, a2[n]);
        }
    }
#else
    float a2[4][4];
#pragma unroll
    for (int n = 0; n < 4; ++n)
#pragma unroll
        for (int j = 0; j < 4; ++j) a2[n][j] = 0.f;
    for (int k = 0; k < 64; ++k) {
        float bv[4];
#pragma unroll
        for (int n = 0; n < 4; ++n) bv[n] = b2f(W2T[n * 16 + r16][k]);
#pragma unroll
        for (int j = 0; j < 4; ++j) {
            float a = b2f(Hb[wave * 16 + kb * 4 + j][k]);
#pragma unroll
            for (int n = 0; n < 4; ++n) a2[n][j] = fmaf(a, bv[n], a2[n][j]);
        }
    }
#endif
#pragma unroll
    for (int j = 0; j < 4; ++j)
#pragma unroll
        for (int n = 0; n < 4; ++n) {
            int f = n * 16 + r16;
            cout[(size_t)(base + wave * 16 + kb * 4 + j) * 64 + f] = f2b(a2[n][j] + b2[f]);
        }
}

// ---------------------------------------------------------------- final projection (fp32 output)
__global__ void k_final(const bfr* __restrict__ net, const float* __restrict__ w,
                        const float* __restrict__ b, float* __restrict__ out, int n) {
    int gw = (blockIdx.x * blockDim.x + threadIdx.x) >> 6;
    int lane = threadIdx.x & 63;
    if (gw >= n) return;
    float p = b2f(net[gw * 64 + lane]) * w[lane];
    for (int m = 1; m < 64; m <<= 1) p += __shfl_xor(p, m);
    if (lane == 0) out[gw] = p + b[0];
}

// ---------------------------------------------------------------- launcher
extern "C" void kernel_launch(void* const* d_in, const int* in_sizes, int n_in,
                              void* d_out, int out_size, void* d_ws, size_t ws_size,
                              hipStream_t stream) {
    const float* net_x    = (const float*)d_in[0];
    const float* pin_in_x = (const float*)d_in[1];
    const float* pin_out_x= (const float*)d_in[2];
    const float* cell_x   = (const float*)d_in[3];
    const int* src1 = (const int*)d_in[4];
    const int* dst1 = (const int*)d_in[5];
    const int* src2 = (const int*)d_in[6];
    const int* dst2 = (const int*)d_in[7];
    const int* src3 = (const int*)d_in[8];
    const int* dst3 = (const int*)d_in[9];
    const int* src4 = (const int*)d_in[10];
    const int* dst4 = (const int*)d_in[11];
    const float* w_ct = (const float*)d_in[12];
    const float* b_ct = (const float*)d_in[13];
    const float* w_net = (const float*)d_in[14];
    const float* b_net = (const float*)d_in[15];
    const float* w_pi = (const float*)d_in[16];
    const float* b_pi = (const float*)d_in[17];
    const float* w_po = (const float*)d_in[18];
    const float* b_po = (const float*)d_in[19];
    const float* w_cs = (const float*)d_in[20];
    const float* b_cs = (const float*)d_in[21];
    const float* g_net = (const float*)d_in[22];
    const float* be_net = (const float*)d_in[23];
    const float* g_pi = (const float*)d_in[24];
    const float* be_pi = (const float*)d_in[25];
    const float* g_po = (const float*)d_in[26];
    const float* be_po = (const float*)d_in[27];
    const float* g_cell = (const float*)d_in[28];
    const float* be_cell = (const float*)d_in[29];
    const float* w_net_up = (const float*)d_in[30];
    const float* b_net_up = (const float*)d_in[31];
    const float* w_pi_up = (const float*)d_in[32];
    const float* b_pi_up = (const float*)d_in[33];
    const float* w_po_up = (const float*)d_in[34];
    const float* b_po_up = (const float*)d_in[35];
    const float* w_cell_up = (const float*)d_in[36];
    const float* b_cell_up = (const float*)d_in[37];
    const float* w_mlp1 = (const float*)d_in[38];
    const float* b_mlp1 = (const float*)d_in[39];
    const float* w_mlp2 = (const float*)d_in[40];
    const float* b_mlp2 = (const float*)d_in[41];
    const float* w_out = (const float*)d_in[42];
    const float* b_out = (const float*)d_in[43];

    size_t off = 0;
    auto take = [&](size_t bytes) {
        size_t c = off;
        off += (bytes + 255) & ~(size_t)255;
        return c;
    };
    char* ws = (char*)d_ws;
    bfr* f_net  = (bfr*)(ws + take((size_t)N_NETN * 64 * 2));
    bfr* f_pi   = (bfr*)(ws + take((size_t)N_PIN * 64 * 2));
    bfr* f_po   = (bfr*)(ws + take((size_t)N_PON * 64 * 2));
    bfr* f_cell = (bfr*)(ws + take((size_t)N_CELLN * 64 * 2));
    bfr* f_cout = (bfr*)(ws + take((size_t)N_CELLN * 64 * 2));
    bfr* f_emb  = (bfr*)(ws + take((size_t)N_CELLN * 8 * 2));
    int*   dcnt   = (int*)(ws + take((size_t)SRC_TOT * 4));
    float* invd   = (float*)dcnt;                 // aliased: in-place int->float
    int*   ccnt   = (int*)(ws + take((size_t)NT_DST * 4));
    int*   cursor = ccnt;                         // aliased: ccnt dead after scan
    int*   rp     = (int*)(ws + take((size_t)(NT_DST + 1) * 4));
    int*   col    = (int*)(ws + take((size_t)E_TOT * 4));
    int*   bsum   = (int*)(ws + take((size_t)NB_CHUNKS * 4));
    // pre-transposed bf16 weights
    bfr* wtb_pi   = (bfr*)(ws + take((size_t)64 * 192 * 2));
    bfr* wtb_cell = (bfr*)(ws + take((size_t)64 * 192 * 2));
    bfr* wtb_po   = (bfr*)(ws + take((size_t)64 * 192 * 2));
    bfr* wtb_net  = (bfr*)(ws + take((size_t)64 * 192 * 2));
    bfr* w1b      = (bfr*)(ws + take((size_t)64 * 96 * 2));
    bfr* w2b      = (bfr*)(ws + take((size_t)64 * 72 * 2));
    (void)in_sizes; (void)n_in; (void)out_size;

    if (ws_size < off) return;   // clean failure instead of memory fault

    dim3 B(256);
    auto cdiv = [](int a, int b) { return (a + b - 1) / b; };

    hipError_t _e0 = hipMemsetAsync(dcnt, 0, (size_t)SRC_TOT * 4, stream); (void)_e0;
    hipError_t _e1 = hipMemsetAsync(ccnt, 0, (size_t)NT_DST * 4, stream); (void)_e1;

    // weight prep
    k_prepw<<<cdiv(64 * 192, 256), B, 0, stream>>>(w_pi_up,   wtb_pi,   192, 64, 192);
    k_prepw<<<cdiv(64 * 192, 256), B, 0, stream>>>(w_cell_up, wtb_cell, 192, 64, 192);
    k_prepw<<<cdiv(64 * 192, 256), B, 0, stream>>>(w_po_up,   wtb_po,   192, 64, 192);
    k_prepw<<<cdiv(64 * 192, 256), B, 0, stream>>>(w_net_up,  wtb_net,  192, 64, 192);
    k_prepw<<<cdiv(64 * 96, 256),  B, 0, stream>>>(w_mlp1,    w1b,       72, 64,  96);
    k_prepw<<<cdiv(64 * 72, 256),  B, 0, stream>>>(w_mlp2,    w2b,       64, 64,  72);

    // source-degree histograms + reciprocals (in place)
    k_hist<<<cdiv(E1, 256), B, 0, stream>>>(src1, E1, dcnt + SB1);
    k_hist<<<cdiv(E2, 256), B, 0, stream>>>(src2, E2, dcnt + SB2);
    k_hist<<<cdiv(E3, 256), B, 0, stream>>>(src3, E3, dcnt + SB3);
    k_hist<<<cdiv(E4, 256), B, 0, stream>>>(src4, E4, dcnt + SB4);
    k_invdeg<<<cdiv(SRC_TOT, 256), B, 0, stream>>>(dcnt, invd, SRC_TOT);

    // dst histograms -> CSR row_ptr
    k_hist<<<cdiv(E1, 256), B, 0, stream>>>(dst1, E1, ccnt + PB_PI);
    k_hist<<<cdiv(E2, 256), B, 0, stream>>>(dst2, E2, ccnt + PB_CELL);
    k_hist<<<cdiv(E3, 256), B, 0, stream>>>(dst3, E3, ccnt + PB_PO);
    k_hist<<<cdiv(E4, 256), B, 0, stream>>>(dst4, E4, ccnt + PB_NET);
    k_scanA<<<NB_CHUNKS, B, 0, stream>>>(ccnt, NT_DST, bsum);
    k_scanB<<<1, B, 0, stream>>>(bsum, NB_CHUNKS);
    k_scanC<<<NB_CHUNKS, B, 0, stream>>>(ccnt, NT_DST, bsum, rp);
    k_copy<<<cdiv(NT_DST, 256), B, 0, stream>>>(rp, cursor, NT_DST);
    k_fill<<<cdiv(E1, 256), B, 0, stream>>>(src1, dst1, E1, PB_PI, cursor, col);
    k_fill<<<cdiv(E2, 256), B, 0, stream>>>(src2, dst2, E2, PB_CELL, cursor, col);
    k_fill<<<cdiv(E3, 256), B, 0, stream>>>(src3, dst3, E3, PB_PO, cursor, col);
    k_fill<<<cdiv(E4, 256), B, 0, stream>>>(src4, dst4, E4, PB_NET, cursor, col);

    // initial embeddings
    k_init_net<<<cdiv(N_NETN * 64, 256), B, 0, stream>>>(net_x, w_net, b_net, f_net, N_NETN);
    k_init_p3<<<cdiv(N_PIN * 64, 256), B, 0, stream>>>(pin_in_x, w_pi, b_pi, f_pi, N_PIN);
    k_init_p3<<<cdiv(N_PON * 64, 256), B, 0, stream>>>(pin_out_x, w_po, b_po, f_po, N_PON);
    k_init_cell<<<cdiv(N_CELLN * 64, 256), B, 0, stream>>>(cell_x, w_cs, b_cs, w_ct, b_ct,
                                                           f_cell, f_emb, N_CELLN);

    for (int l = 0; l < 4; ++l) {
        k_update<<<cdiv(N_PIN, 64), B, 0, stream>>>(
            N_PIN, f_pi, f_net, rp + PB_PI, col, invd + SB1, wtb_pi, b_pi_up, g_pi, be_pi);
        k_update<<<cdiv(N_CELLN, 64), B, 0, stream>>>(
            N_CELLN, f_cell, f_pi, rp + PB_CELL, col, invd + SB2, wtb_cell, b_cell_up, g_cell, be_cell);
        k_mlp<<<N_CELLN / 64, B, 0, stream>>>(f_cell, f_emb, w1b, b_mlp1, w2b, b_mlp2, f_cout);
        k_update<<<cdiv(N_PON, 64), B, 0, stream>>>(
            N_PON, f_po, f_cout, rp + PB_PO, col, invd + SB3, wtb_po, b_po_up, g_po, be_po);
        k_update<<<cdiv(N_NETN, 64), B, 0, stream>>>(
            N_NETN, f_net, f_po, rp + PB_NET, col, invd + SB4, wtb_net, b_net_up, g_net, be_net);
    }

    k_final<<<cdiv(N_NETN * 64, 256), B, 0, stream>>>(f_net, w_out, b_out, (float*)d_out, N_NETN);
}